// Round 8
// baseline (2797.545 us; speedup 1.0000x reference)
//
#include <hip/hip_runtime.h>

#define DIM 128
#define NBLK 64       // partition blocks
#define MAXTB 2560    // max total buckets (3 * ceil(50000/64) = 2346)

static inline size_t align256(size_t x) { return (x + 255) & ~(size_t)255; }

// ---------------- out-degree counting (for GEMM pre-scale), all 3 relations ----------------
__global__ void k_dout(const int* __restrict__ s1, int E1,
                       const int* __restrict__ s2, int E2,
                       const int* __restrict__ s3, int E3,
                       int* __restrict__ dout, int NM) {
  int i = blockIdx.x * blockDim.x + threadIdx.x;
  int st = gridDim.x * blockDim.x;
  int ET = E1 + E2 + E3;
  for (; i < ET; i += st) {
    const int* sp; int j, r;
    if (i < E1) { r = 0; j = i; sp = s1; }
    else if (i < E1 + E2) { r = 1; j = i - E1; sp = s2; }
    else { r = 2; j = i - E1 - E2; sp = s3; }
    atomicAdd(&dout[r * NM + sp[j]], 1);
  }
}

// ---------------- per-(bucket,block) histogram ----------------
__global__ __launch_bounds__(256) void k_hist(const int* __restrict__ d1, int E1,
                                              const int* __restrict__ d2, int E2,
                                              const int* __restrict__ d3, int E3,
                                              int* __restrict__ Hmat, int NB, int TB) {
  __shared__ int hl[MAXTB];
  int t = threadIdx.x, b = blockIdx.x;
  for (int k = t; k < TB; k += 256) hl[k] = 0;
  __syncthreads();
  int ET = E1 + E2 + E3;
  int CH = (ET + NBLK - 1) / NBLK;
  int lo = b * CH, hi = min(lo + CH, ET);
  for (int i = lo + t; i < hi; i += 256) {
    const int* dp; int j, r;
    if (i < E1) { r = 0; j = i; dp = d1; }
    else if (i < E1 + E2) { r = 1; j = i - E1; dp = d2; }
    else { r = 2; j = i - E1 - E2; dp = d3; }
    int kb = r * NB + (dp[j] >> 6);
    atomicAdd(&hl[kb], 1);
  }
  __syncthreads();
  for (int k = t; k < TB; k += 256) Hmat[(size_t)k * NBLK + b] = hl[k];
}

// ---------------- multi-block scan (bucket-major matrix) ----------------
__global__ __launch_bounds__(256) void k_scan1(const int* __restrict__ cnt,
                                               int* __restrict__ part, int M) {
  __shared__ int wsh[4];
  int t = threadIdx.x;
  int base = blockIdx.x * 2048 + t * 8;
  int s = 0;
  if (base + 8 <= M) {
    const int4* p = (const int4*)(cnt + base);
    int4 a = p[0], b = p[1];
    s = a.x + a.y + a.z + a.w + b.x + b.y + b.z + b.w;
  } else {
    for (int j = 0; j < 8; ++j) { int idx = base + j; if (idx < M) s += cnt[idx]; }
  }
#pragma unroll
  for (int off = 32; off; off >>= 1) s += __shfl_down(s, off, 64);
  int lane = t & 63, wid = t >> 6;
  if (lane == 0) wsh[wid] = s;
  __syncthreads();
  if (t == 0) part[blockIdx.x] = wsh[0] + wsh[1] + wsh[2] + wsh[3];
}

__global__ __launch_bounds__(256) void k_scan2(int* __restrict__ part, int B,
                                               int* __restrict__ rp, int M) {
  __shared__ int sh[256];
  int t = threadIdx.x;
  sh[t] = (t < B) ? part[t] : 0;
  __syncthreads();
  for (int off = 1; off < 256; off <<= 1) {
    int v = (t >= off) ? sh[t - off] : 0;
    __syncthreads();
    sh[t] += v;
    __syncthreads();
  }
  if (t < B) part[t] = t ? sh[t - 1] : 0;
  if (t == 0) rp[M] = sh[255];
}

__global__ __launch_bounds__(256) void k_scan3(const int* __restrict__ cnt,
                                               const int* __restrict__ part,
                                               int* __restrict__ rp,
                                               int* __restrict__ cur, int M) {
  __shared__ int wsh[4];
  int t = threadIdx.x, lane = t & 63, wid = t >> 6;
  int base = blockIdx.x * 2048 + t * 8;
  int v[8];
  if (base + 8 <= M) {
    const int4* p = (const int4*)(cnt + base);
    int4 a = p[0], b = p[1];
    v[0] = a.x; v[1] = a.y; v[2] = a.z; v[3] = a.w;
    v[4] = b.x; v[5] = b.y; v[6] = b.z; v[7] = b.w;
  } else {
    for (int j = 0; j < 8; ++j) { int idx = base + j; v[j] = (idx < M) ? cnt[idx] : 0; }
  }
  int ts = 0;
#pragma unroll
  for (int j = 0; j < 8; ++j) ts += v[j];
  int incl = ts;
#pragma unroll
  for (int d = 1; d < 64; d <<= 1) { int u = __shfl_up(incl, d, 64); if (lane >= d) incl += u; }
  if (lane == 63) wsh[wid] = incl;
  __syncthreads();
  int woff = 0;
  for (int w = 0; w < wid; ++w) woff += wsh[w];
  int run = part[blockIdx.x] + woff + incl - ts;
#pragma unroll
  for (int j = 0; j < 8; ++j) {
    int idx = base + j;
    if (idx < M) { rp[idx] = run; cur[idx] = run; }
    run += v[j];
  }
}

// ---------------- scatter edges into bucket-grouped buffer (LDS cursors) ----------------
__global__ __launch_bounds__(256) void k_scatter(const int* __restrict__ s1, const int* __restrict__ d1, int E1,
                                                 const int* __restrict__ s2, const int* __restrict__ d2, int E2,
                                                 const int* __restrict__ s3, const int* __restrict__ d3, int E3,
                                                 const int* __restrict__ rp,
                                                 unsigned* __restrict__ ebuf, int NB, int TB) {
  __shared__ int curl[MAXTB];
  int t = threadIdx.x, b = blockIdx.x;
  for (int k = t; k < TB; k += 256) curl[k] = rp[(size_t)k * NBLK + b];
  __syncthreads();
  int ET = E1 + E2 + E3;
  int CH = (ET + NBLK - 1) / NBLK;
  int lo = b * CH, hi = min(lo + CH, ET);
  for (int i = lo + t; i < hi; i += 256) {
    const int* sp; const int* dp; int j, r;
    if (i < E1) { r = 0; j = i; sp = s1; dp = d1; }
    else if (i < E1 + E2) { r = 1; j = i - E1; sp = s2; dp = d2; }
    else { r = 2; j = i - E1 - E2; sp = s3; dp = d3; }
    int dst = dp[j];
    int kb = r * NB + (dst >> 6);
    int pos = atomicAdd(&curl[kb], 1);
    ebuf[pos] = ((unsigned)(dst & 63) << 16) | (unsigned)sp[j];
  }
}

// ---------------- bucket aggregation: 64 dst rows in LDS, gather m rows, scale ----------------
__global__ __launch_bounds__(256) void k_agg(const float* __restrict__ m,
                                             const unsigned* __restrict__ ebuf,
                                             const int* __restrict__ rp,
                                             int bucket0, float* __restrict__ z, int Ndst) {
  __shared__ float acc[64][DIM];
  __shared__ int dcnt[64];
  int t = threadIdx.x, lane = t & 63, wid = t >> 6;
  for (int i = t; i < 64 * DIM; i += 256) ((float*)acc)[i] = 0.f;
  for (int i = t; i < 64; i += 256) dcnt[i] = 0;
  __syncthreads();
  int k = bucket0 + blockIdx.x;
  int start = rp[(size_t)k * NBLK];
  int end = rp[(size_t)(k + 1) * NBLK];
  for (int e = start + wid; e < end; e += 4) {
    unsigned p = ebuf[e];
    int src = p & 0xFFFF;
    int dl = p >> 16;
    const float2 v = *(const float2*)(m + (size_t)src * DIM + 2 * lane);
    atomicAdd(&acc[dl][2 * lane], v.x);
    atomicAdd(&acc[dl][2 * lane + 1], v.y);
    if (lane == 0) atomicAdd(&dcnt[dl], 1);
  }
  __syncthreads();
  int base = blockIdx.x * 64;
  for (int row = wid; row < 64; row += 4) {
    int n = base + row;
    if (n < Ndst) {
      float sc = rsqrtf(fmaxf((float)dcnt[row], 1.0f));
      float2 o;
      o.x = acc[row][2 * lane] * sc;
      o.y = acc[row][2 * lane + 1] * sc;
      *(float2*)(z + (size_t)n * DIM + 2 * lane) = o;
    }
  }
}

// ---------------- m = (h * rsqrt(max(deg_out,1))) @ W  (wave per node, 512 thr) ----------------
__global__ __launch_bounds__(512) void k_gemm(const float* __restrict__ h,
                                              const float* __restrict__ W,
                                              const int* __restrict__ degout,
                                              float* __restrict__ m, int N) {
  __shared__ float Wl[DIM * DIM];
  for (int i = threadIdx.x; i < DIM * DIM; i += 512) Wl[i] = W[i];
  __syncthreads();
  int lane = threadIdx.x & 63, wid = threadIdx.x >> 6;
  int gw = blockIdx.x * 8 + wid, nw = gridDim.x * 8;
  for (int n = gw; n < N; n += nw) {
    float s = rsqrtf(fmaxf((float)degout[n], 1.0f));
    const float4* h4 = (const float4*)(h + (size_t)n * DIM);
    float ax = 0.f, ay = 0.f;
#pragma unroll 4
    for (int k4 = 0; k4 < 32; ++k4) {
      float4 hv = h4[k4];
      int k = k4 * 4;
      float2 w0 = *(const float2*)&Wl[(k + 0) * DIM + 2 * lane];
      float2 w1 = *(const float2*)&Wl[(k + 1) * DIM + 2 * lane];
      float2 w2 = *(const float2*)&Wl[(k + 2) * DIM + 2 * lane];
      float2 w3 = *(const float2*)&Wl[(k + 3) * DIM + 2 * lane];
      ax = fmaf(hv.x, w0.x, ax); ay = fmaf(hv.x, w0.y, ay);
      ax = fmaf(hv.y, w1.x, ax); ay = fmaf(hv.y, w1.y, ay);
      ax = fmaf(hv.z, w2.x, ax); ay = fmaf(hv.z, w2.y, ay);
      ax = fmaf(hv.w, w3.x, ax); ay = fmaf(hv.w, w3.y, ay);
    }
    float2 o; o.x = s * ax; o.y = s * ay;
    *(float2*)(m + (size_t)n * DIM + 2 * lane) = o;
  }
}

// ---------------- attention scores (512 thr) ----------------
__global__ __launch_bounds__(512) void k_att(const float* __restrict__ z1,
                                             const float* __restrict__ z2,
                                             const float* __restrict__ attW,
                                             const float* __restrict__ attb,
                                             const float* __restrict__ attq,
                                             float* __restrict__ wsum, int N) {
  __shared__ float Wl[DIM * DIM];
  for (int i = threadIdx.x; i < DIM * DIM; i += 512) Wl[i] = attW[i];
  int lane = threadIdx.x & 63, wid = threadIdx.x >> 6;
  float b0 = attb[2 * lane], b1 = attb[2 * lane + 1];
  float q0 = attq[2 * lane], q1 = attq[2 * lane + 1];
  __syncthreads();
  int gw = blockIdx.x * 8 + wid, nw = gridDim.x * 8;
  float a1 = 0.f, a2 = 0.f;
  for (int n = gw; n < N; n += nw) {
    const float4* p1 = (const float4*)(z1 + (size_t)n * DIM);
    const float4* p2 = (const float4*)(z2 + (size_t)n * DIM);
    float c1x = 0, c1y = 0, c2x = 0, c2y = 0;
#pragma unroll 4
    for (int k4 = 0; k4 < 32; ++k4) {
      float4 u = p1[k4];
      float4 v = p2[k4];
      int k = k4 * 4;
      float2 w0 = *(const float2*)&Wl[(k + 0) * DIM + 2 * lane];
      float2 w1 = *(const float2*)&Wl[(k + 1) * DIM + 2 * lane];
      float2 w2 = *(const float2*)&Wl[(k + 2) * DIM + 2 * lane];
      float2 w3 = *(const float2*)&Wl[(k + 3) * DIM + 2 * lane];
      c1x = fmaf(u.x, w0.x, c1x); c1y = fmaf(u.x, w0.y, c1y);
      c2x = fmaf(v.x, w0.x, c2x); c2y = fmaf(v.x, w0.y, c2y);
      c1x = fmaf(u.y, w1.x, c1x); c1y = fmaf(u.y, w1.y, c1y);
      c2x = fmaf(v.y, w1.x, c2x); c2y = fmaf(v.y, w1.y, c2y);
      c1x = fmaf(u.z, w2.x, c1x); c1y = fmaf(u.z, w2.y, c1y);
      c2x = fmaf(v.z, w2.x, c2x); c2y = fmaf(v.z, w2.y, c2y);
      c1x = fmaf(u.w, w3.x, c1x); c1y = fmaf(u.w, w3.y, c1y);
      c2x = fmaf(v.w, w3.x, c2x); c2y = fmaf(v.w, w3.y, c2y);
    }
    a1 += tanhf(c1x + b0) * q0 + tanhf(c1y + b1) * q1;
    a2 += tanhf(c2x + b0) * q0 + tanhf(c2y + b1) * q1;
  }
#pragma unroll
  for (int off = 32; off; off >>= 1) {
    a1 += __shfl_down(a1, off, 64);
    a2 += __shfl_down(a2, off, 64);
  }
  __syncthreads();  // done reading Wl; reuse as scratch
  if (lane == 0) { Wl[wid] = a1; Wl[8 + wid] = a2; }
  __syncthreads();
  if (threadIdx.x == 0) {
    float s1 = 0, s2 = 0;
    for (int w = 0; w < 8; ++w) { s1 += Wl[w]; s2 += Wl[8 + w]; }
    atomicAdd(&wsum[0], s1);
    atomicAdd(&wsum[1], s2);
  }
}

// ---------------- x = beta1*z1 + beta2*z2 (in place over z1) ----------------
__global__ void k_combine(float* __restrict__ x, const float* __restrict__ z2,
                          const float* __restrict__ wsum, float invN, int total4) {
  float w1 = wsum[0] * invN, w2 = wsum[1] * invN;
  float mx = fmaxf(w1, w2);
  float e1 = expf(w1 - mx), e2 = expf(w2 - mx);
  float inv = 1.f / (e1 + e2);
  float b1 = e1 * inv, b2 = e2 * inv;
  float4* x4 = (float4*)x;
  const float4* z4 = (const float4*)z2;
  int i = blockIdx.x * blockDim.x + threadIdx.x;
  int st = gridDim.x * blockDim.x;
  for (; i < total4; i += st) {
    float4 a = x4[i], b = z4[i];
    a.x = b1 * a.x + b2 * b.x;
    a.y = b1 * a.y + b2 * b.y;
    a.z = b1 * a.z + b2 * b.z;
    a.w = b1 * a.w + b2 * b.w;
    x4[i] = a;
  }
}

// ---------------- column stats for BOTH outputs ----------------
__global__ __launch_bounds__(128) void k_stats2(const float* __restrict__ xp,
                                                const float* __restrict__ xa,
                                                int NP, int NA, float* __restrict__ st) {
  int d = threadIdx.x;
  float sp = 0, qp = 0, sa = 0, qa = 0;
  for (int n = blockIdx.x; n < NP; n += gridDim.x) {
    float v = xp[(size_t)n * DIM + d]; sp += v; qp += v * v;
  }
  for (int n = blockIdx.x; n < NA; n += gridDim.x) {
    float v = xa[(size_t)n * DIM + d]; sa += v; qa += v * v;
  }
  atomicAdd(&st[d], sp);
  atomicAdd(&st[DIM + d], qp);
  atomicAdd(&st[2 * DIM + d], sa);
  atomicAdd(&st[3 * DIM + d], qa);
}

// ---------------- BatchNorm + row L2 normalize, wave per row, both outputs ----------------
__global__ __launch_bounds__(256) void k_post2(float* __restrict__ xp, float* __restrict__ xa,
                                               const float* __restrict__ st,
                                               const float* __restrict__ gamma,
                                               const float* __restrict__ beta,
                                               int NP, int NA) {
  int lane = threadIdx.x & 63;
  int wv = blockIdx.x * 4 + (threadIdx.x >> 6), nw = gridDim.x * 4;
  int d0 = 2 * lane, d1 = d0 + 1;
  {
    float invN = 1.f / (float)NP;
    float mu0 = st[d0] * invN, mu1 = st[d1] * invN;
    float g0 = gamma[d0] * rsqrtf(st[DIM + d0] * invN - mu0 * mu0 + 1e-5f);
    float g1 = gamma[d1] * rsqrtf(st[DIM + d1] * invN - mu1 * mu1 + 1e-5f);
    float b0 = beta[d0], b1 = beta[d1];
    for (int n = wv; n < NP; n += nw) {
      float2 v = *(float2*)(xp + (size_t)n * DIM + d0);
      float y0 = fmaf(v.x - mu0, g0, b0);
      float y1 = fmaf(v.y - mu1, g1, b1);
      float p = y0 * y0 + y1 * y1;
#pragma unroll
      for (int off = 32; off; off >>= 1) p += __shfl_xor(p, off, 64);
      float r = rsqrtf(p + 1e-12f);
      float2 o; o.x = y0 * r; o.y = y1 * r;
      *(float2*)(xp + (size_t)n * DIM + d0) = o;
    }
  }
  {
    float invN = 1.f / (float)NA;
    float mu0 = st[2 * DIM + d0] * invN, mu1 = st[2 * DIM + d1] * invN;
    float g0 = gamma[d0] * rsqrtf(st[3 * DIM + d0] * invN - mu0 * mu0 + 1e-5f);
    float g1 = gamma[d1] * rsqrtf(st[3 * DIM + d1] * invN - mu1 * mu1 + 1e-5f);
    float b0 = beta[d0], b1 = beta[d1];
    for (int n = wv; n < NA; n += nw) {
      float2 v = *(float2*)(xa + (size_t)n * DIM + d0);
      float y0 = fmaf(v.x - mu0, g0, b0);
      float y1 = fmaf(v.y - mu1, g1, b1);
      float p = y0 * y0 + y1 * y1;
#pragma unroll
      for (int off = 32; off; off >>= 1) p += __shfl_xor(p, off, 64);
      float r = rsqrtf(p + 1e-12f);
      float2 o; o.x = y0 * r; o.y = y1 * r;
      *(float2*)(xa + (size_t)n * DIM + d0) = o;
    }
  }
}

extern "C" void kernel_launch(void* const* d_in, const int* in_sizes, int n_in,
                              void* d_out, int out_size, void* d_ws, size_t ws_size,
                              hipStream_t stream) {
  const float* h_paper  = (const float*)d_in[0];
  const float* h_author = (const float*)d_in[1];
  const float* W_r1 = (const float*)d_in[2];
  const float* W_r2 = (const float*)d_in[3];
  const float* W_r3 = (const float*)d_in[4];
  const float* att_W = (const float*)d_in[5];
  const float* att_b = (const float*)d_in[6];
  const float* att_q = (const float*)d_in[7];
  const float* bn_g = (const float*)d_in[8];
  const float* bn_b = (const float*)d_in[9];
  const int* src_r1 = (const int*)d_in[10];
  const int* dst_r1 = (const int*)d_in[11];
  const int* src_r2 = (const int*)d_in[12];
  const int* dst_r2 = (const int*)d_in[13];
  const int* src_r3 = (const int*)d_in[14];
  const int* dst_r3 = (const int*)d_in[15];

  int NP = in_sizes[0] / DIM;
  int NA = in_sizes[1] / DIM;
  int E1 = in_sizes[10], E2 = in_sizes[12], E3 = in_sizes[14];
  int ET = E1 + E2 + E3;
  int NM = NP > NA ? NP : NA;
  int NB = (NM + 63) >> 6;              // buckets per relation (dst/64)
  int TB = 3 * NB;                      // total buckets
  int M = TB * NBLK;                    // offset-matrix length
  int B = (M + 2047) / 2048;            // scan partial blocks (<=256)

  char* ws = (char*)d_ws;
  size_t off = 0;
  float* m_buf = (float*)(ws + off);    off += align256((size_t)NM * DIM * 4);
  float* z2    = (float*)(ws + off);    off += align256((size_t)NP * DIM * 4);
  unsigned* ebuf = (unsigned*)(ws + off); off += align256((size_t)ET * 4);
  int* Hmat    = (int*)(ws + off);      off += align256((size_t)M * 4);
  int* rp      = (int*)(ws + off);      off += align256(((size_t)M + 1) * 4);
  int* curscr  = (int*)(ws + off);      off += align256((size_t)M * 4);
  int* part    = (int*)(ws + off);      off += align256(256 * 4);
  size_t zoff = off;  // zero-initialized region
  int* dout    = (int*)(ws + off);      off += (size_t)3 * NM * 4;
  float* wsum  = (float*)(ws + off);    off += 2 * 4;
  float* stats = (float*)(ws + off);    off += 4 * DIM * 4;
  size_t zbytes = off - zoff;

  float* xp = (float*)d_out;                       // papers (z_p1 staging)
  float* xa = (float*)d_out + (size_t)NP * DIM;    // authors (z_a1 staging)

  hipMemsetAsync(ws + zoff, 0, zbytes, stream);

  // out-degrees for GEMM pre-scale
  k_dout<<<2048, 256, 0, stream>>>(src_r1, E1, src_r2, E2, src_r3, E3, dout, NM);

  // bucket partition: histogram -> scan -> scatter
  k_hist<<<NBLK, 256, 0, stream>>>(dst_r1, E1, dst_r2, E2, dst_r3, E3, Hmat, NB, TB);
  k_scan1<<<B, 256, 0, stream>>>(Hmat, part, M);
  k_scan2<<<1, 256, 0, stream>>>(part, B, rp, M);
  k_scan3<<<B, 256, 0, stream>>>(Hmat, part, rp, curscr, M);
  k_scatter<<<NBLK, 256, 0, stream>>>(src_r1, dst_r1, E1, src_r2, dst_r2, E2,
                                      src_r3, dst_r3, E3, rp, ebuf, NB, TB);

  // r1: author -> paper (z_p1 -> xp)
  k_gemm<<<512, 512, 0, stream>>>(h_author, W_r1, dout, m_buf, NA);
  k_agg<<<NB, 256, 0, stream>>>(m_buf, ebuf, rp, 0, xp, NP);
  // r2: paper -> paper (z_p2 -> ws)
  k_gemm<<<512, 512, 0, stream>>>(h_paper, W_r2, dout + NM, m_buf, NP);
  k_agg<<<NB, 256, 0, stream>>>(m_buf, ebuf, rp, NB, z2, NP);
  // r3: author -> author (z_a1 -> xa; softmax over 1 relation == identity)
  k_gemm<<<512, 512, 0, stream>>>(h_author, W_r3, dout + 2 * NM, m_buf, NA);
  k_agg<<<NB, 256, 0, stream>>>(m_buf, ebuf, rp, 2 * NB, xa, NA);

  // semantic attention (papers)
  k_att<<<512, 512, 0, stream>>>(xp, z2, att_W, att_b, att_q, wsum, NP);
  k_combine<<<2048, 256, 0, stream>>>(xp, z2, wsum, 1.0f / (float)NP, NP * DIM / 4);

  // BatchNorm stats + apply + row L2 for both outputs
  k_stats2<<<1024, 128, 0, stream>>>(xp, xa, NP, NA, stats);
  k_post2<<<2048, 256, 0, stream>>>(xp, xa, stats, bn_g, bn_b, NP, NA);
}

// Round 9
// 1014.743 us; speedup vs baseline: 2.7569x; 2.7569x over previous
//
#include <hip/hip_runtime.h>

#define DIM 128
#define NBLK 64       // partition blocks (first-level)
#define MAXTB 2560    // max total buckets (3 * ceil(50000/64) = 2346)

static inline size_t align256(size_t x) { return (x + 255) & ~(size_t)255; }

// ---------------- out-degree counting (for GEMM pre-scale), all 3 relations ----------------
__global__ void k_dout(const int* __restrict__ s1, int E1,
                       const int* __restrict__ s2, int E2,
                       const int* __restrict__ s3, int E3,
                       int* __restrict__ dout, int NM) {
  int i = blockIdx.x * blockDim.x + threadIdx.x;
  int st = gridDim.x * blockDim.x;
  int ET = E1 + E2 + E3;
  for (; i < ET; i += st) {
    const int* sp; int j, r;
    if (i < E1) { r = 0; j = i; sp = s1; }
    else if (i < E1 + E2) { r = 1; j = i - E1; sp = s2; }
    else { r = 2; j = i - E1 - E2; sp = s3; }
    atomicAdd(&dout[r * NM + sp[j]], 1);
  }
}

// ---------------- per-(bucket,block) histogram ----------------
__global__ __launch_bounds__(256) void k_hist(const int* __restrict__ d1, int E1,
                                              const int* __restrict__ d2, int E2,
                                              const int* __restrict__ d3, int E3,
                                              int* __restrict__ Hmat, int NB, int TB) {
  __shared__ int hl[MAXTB];
  int t = threadIdx.x, b = blockIdx.x;
  for (int k = t; k < TB; k += 256) hl[k] = 0;
  __syncthreads();
  int ET = E1 + E2 + E3;
  int CH = (ET + NBLK - 1) / NBLK;
  int lo = b * CH, hi = min(lo + CH, ET);
  for (int i = lo + t; i < hi; i += 256) {
    const int* dp; int j, r;
    if (i < E1) { r = 0; j = i; dp = d1; }
    else if (i < E1 + E2) { r = 1; j = i - E1; dp = d2; }
    else { r = 2; j = i - E1 - E2; dp = d3; }
    int kb = r * NB + (dp[j] >> 6);
    atomicAdd(&hl[kb], 1);
  }
  __syncthreads();
  for (int k = t; k < TB; k += 256) Hmat[(size_t)k * NBLK + b] = hl[k];
}

// ---------------- multi-block scan (bucket-major matrix) ----------------
__global__ __launch_bounds__(256) void k_scan1(const int* __restrict__ cnt,
                                               int* __restrict__ part, int M) {
  __shared__ int wsh[4];
  int t = threadIdx.x;
  int base = blockIdx.x * 2048 + t * 8;
  int s = 0;
  if (base + 8 <= M) {
    const int4* p = (const int4*)(cnt + base);
    int4 a = p[0], b = p[1];
    s = a.x + a.y + a.z + a.w + b.x + b.y + b.z + b.w;
  } else {
    for (int j = 0; j < 8; ++j) { int idx = base + j; if (idx < M) s += cnt[idx]; }
  }
#pragma unroll
  for (int off = 32; off; off >>= 1) s += __shfl_down(s, off, 64);
  int lane = t & 63, wid = t >> 6;
  if (lane == 0) wsh[wid] = s;
  __syncthreads();
  if (t == 0) part[blockIdx.x] = wsh[0] + wsh[1] + wsh[2] + wsh[3];
}

__global__ __launch_bounds__(256) void k_scan2(int* __restrict__ part, int B,
                                               int* __restrict__ rp, int M) {
  __shared__ int sh[256];
  int t = threadIdx.x;
  sh[t] = (t < B) ? part[t] : 0;
  __syncthreads();
  for (int off = 1; off < 256; off <<= 1) {
    int v = (t >= off) ? sh[t - off] : 0;
    __syncthreads();
    sh[t] += v;
    __syncthreads();
  }
  if (t < B) part[t] = t ? sh[t - 1] : 0;
  if (t == 0) rp[M] = sh[255];
}

__global__ __launch_bounds__(256) void k_scan3(const int* __restrict__ cnt,
                                               const int* __restrict__ part,
                                               int* __restrict__ rp, int M) {
  __shared__ int wsh[4];
  int t = threadIdx.x, lane = t & 63, wid = t >> 6;
  int base = blockIdx.x * 2048 + t * 8;
  int v[8];
  if (base + 8 <= M) {
    const int4* p = (const int4*)(cnt + base);
    int4 a = p[0], b = p[1];
    v[0] = a.x; v[1] = a.y; v[2] = a.z; v[3] = a.w;
    v[4] = b.x; v[5] = b.y; v[6] = b.z; v[7] = b.w;
  } else {
    for (int j = 0; j < 8; ++j) { int idx = base + j; v[j] = (idx < M) ? cnt[idx] : 0; }
  }
  int ts = 0;
#pragma unroll
  for (int j = 0; j < 8; ++j) ts += v[j];
  int incl = ts;
#pragma unroll
  for (int d = 1; d < 64; d <<= 1) { int u = __shfl_up(incl, d, 64); if (lane >= d) incl += u; }
  if (lane == 63) wsh[wid] = incl;
  __syncthreads();
  int woff = 0;
  for (int w = 0; w < wid; ++w) woff += wsh[w];
  int run = part[blockIdx.x] + woff + incl - ts;
#pragma unroll
  for (int j = 0; j < 8; ++j) {
    int idx = base + j;
    if (idx < M) rp[idx] = run;
    run += v[j];
  }
}

// ---------------- scatter edges into bucket-grouped buffer (LDS cursors) ----------------
__global__ __launch_bounds__(256) void k_scatter(const int* __restrict__ s1, const int* __restrict__ d1, int E1,
                                                 const int* __restrict__ s2, const int* __restrict__ d2, int E2,
                                                 const int* __restrict__ s3, const int* __restrict__ d3, int E3,
                                                 const int* __restrict__ rp,
                                                 unsigned* __restrict__ ebuf, int NB, int TB) {
  __shared__ int curl[MAXTB];
  int t = threadIdx.x, b = blockIdx.x;
  for (int k = t; k < TB; k += 256) curl[k] = rp[(size_t)k * NBLK + b];
  __syncthreads();
  int ET = E1 + E2 + E3;
  int CH = (ET + NBLK - 1) / NBLK;
  int lo = b * CH, hi = min(lo + CH, ET);
  for (int i = lo + t; i < hi; i += 256) {
    const int* sp; const int* dp; int j, r;
    if (i < E1) { r = 0; j = i; sp = s1; dp = d1; }
    else if (i < E1 + E2) { r = 1; j = i - E1; sp = s2; dp = d2; }
    else { r = 2; j = i - E1 - E2; sp = s3; dp = d3; }
    int dst = dp[j];
    int kb = r * NB + (dst >> 6);
    int pos = atomicAdd(&curl[kb], 1);
    ebuf[pos] = ((unsigned)(dst & 63) << 16) | (unsigned)sp[j];
  }
}

// ---------------- second level: sort each bucket by dst, emit per-dst CSR ----------------
__global__ __launch_bounds__(256) void k_bsort(const unsigned* __restrict__ ebuf,
                                               const int* __restrict__ rp,
                                               unsigned short* __restrict__ ebuf2,
                                               int* __restrict__ rp2, int* __restrict__ deg,
                                               int NB, int NM) {
  __shared__ int hist[64];
  __shared__ int cursor[64];
  int t = threadIdx.x;
  int k = blockIdx.x;
  if (t < 64) hist[t] = 0;
  __syncthreads();
  int start = rp[(size_t)k * NBLK];
  int end = rp[(size_t)(k + 1) * NBLK];
  for (int e = start + t; e < end; e += 256)
    atomicAdd(&hist[ebuf[e] >> 16], 1);
  __syncthreads();
  if (t < 64) {
    int v = hist[t];
    int incl = v;
#pragma unroll
    for (int d = 1; d < 64; d <<= 1) { int u = __shfl_up(incl, d, 64); if (t >= d) incl += u; }
    int excl = incl - v;
    cursor[t] = start + excl;
    int r = k / NB, bb = k - r * NB;
    int ld = bb * 64 + t;
    if (ld < NM) {
      rp2[r * NM + ld] = start + excl;
      deg[r * NM + ld] = v;
    }
  }
  __syncthreads();
  for (int e = start + t; e < end; e += 256) {
    unsigned p = ebuf[e];
    int pos = atomicAdd(&cursor[p >> 16], 1);
    ebuf2[pos] = (unsigned short)(p & 0xFFFF);
  }
}

// ---------------- pull aggregation (wave per dst, sorted ushort srcs) ----------------
__global__ __launch_bounds__(256) void k_pull2(const float* __restrict__ m,
                                               const int* __restrict__ rp2,
                                               const int* __restrict__ deg,
                                               const unsigned short* __restrict__ ebuf2,
                                               float* __restrict__ z, int N) {
  int lane = threadIdx.x & 63, wid = threadIdx.x >> 6;
  int gw = blockIdx.x * 4 + wid, nw = gridDim.x * 4;
  for (int n = gw; n < N; n += nw) {
    int b = rp2[n], d = deg[n];
    float ax = 0.f, ay = 0.f;
    for (int e = b; e < b + d; ++e) {
      int s = ebuf2[e];
      float2 v = *(const float2*)(m + (size_t)s * DIM + 2 * lane);
      ax += v.x; ay += v.y;
    }
    float sc = rsqrtf(fmaxf((float)d, 1.0f));
    float2 o; o.x = ax * sc; o.y = ay * sc;
    *(float2*)(z + (size_t)n * DIM + 2 * lane) = o;
  }
}

// ---------------- m = (h * rsqrt(max(deg_out,1))) @ W  (wave per node, 512 thr) ----------------
__global__ __launch_bounds__(512) void k_gemm(const float* __restrict__ h,
                                              const float* __restrict__ W,
                                              const int* __restrict__ degout,
                                              float* __restrict__ m, int N) {
  __shared__ float Wl[DIM * DIM];
  for (int i = threadIdx.x; i < DIM * DIM; i += 512) Wl[i] = W[i];
  __syncthreads();
  int lane = threadIdx.x & 63, wid = threadIdx.x >> 6;
  int gw = blockIdx.x * 8 + wid, nw = gridDim.x * 8;
  for (int n = gw; n < N; n += nw) {
    float s = rsqrtf(fmaxf((float)degout[n], 1.0f));
    const float4* h4 = (const float4*)(h + (size_t)n * DIM);
    float ax = 0.f, ay = 0.f;
#pragma unroll 4
    for (int k4 = 0; k4 < 32; ++k4) {
      float4 hv = h4[k4];
      int k = k4 * 4;
      float2 w0 = *(const float2*)&Wl[(k + 0) * DIM + 2 * lane];
      float2 w1 = *(const float2*)&Wl[(k + 1) * DIM + 2 * lane];
      float2 w2 = *(const float2*)&Wl[(k + 2) * DIM + 2 * lane];
      float2 w3 = *(const float2*)&Wl[(k + 3) * DIM + 2 * lane];
      ax = fmaf(hv.x, w0.x, ax); ay = fmaf(hv.x, w0.y, ay);
      ax = fmaf(hv.y, w1.x, ax); ay = fmaf(hv.y, w1.y, ay);
      ax = fmaf(hv.z, w2.x, ax); ay = fmaf(hv.z, w2.y, ay);
      ax = fmaf(hv.w, w3.x, ax); ay = fmaf(hv.w, w3.y, ay);
    }
    float2 o; o.x = s * ax; o.y = s * ay;
    *(float2*)(m + (size_t)n * DIM + 2 * lane) = o;
  }
}

// ---------------- attention scores (512 thr) ----------------
__global__ __launch_bounds__(512) void k_att(const float* __restrict__ z1,
                                             const float* __restrict__ z2,
                                             const float* __restrict__ attW,
                                             const float* __restrict__ attb,
                                             const float* __restrict__ attq,
                                             float* __restrict__ wsum, int N) {
  __shared__ float Wl[DIM * DIM];
  for (int i = threadIdx.x; i < DIM * DIM; i += 512) Wl[i] = attW[i];
  int lane = threadIdx.x & 63, wid = threadIdx.x >> 6;
  float b0 = attb[2 * lane], b1 = attb[2 * lane + 1];
  float q0 = attq[2 * lane], q1 = attq[2 * lane + 1];
  __syncthreads();
  int gw = blockIdx.x * 8 + wid, nw = gridDim.x * 8;
  float a1 = 0.f, a2 = 0.f;
  for (int n = gw; n < N; n += nw) {
    const float4* p1 = (const float4*)(z1 + (size_t)n * DIM);
    const float4* p2 = (const float4*)(z2 + (size_t)n * DIM);
    float c1x = 0, c1y = 0, c2x = 0, c2y = 0;
#pragma unroll 4
    for (int k4 = 0; k4 < 32; ++k4) {
      float4 u = p1[k4];
      float4 v = p2[k4];
      int k = k4 * 4;
      float2 w0 = *(const float2*)&Wl[(k + 0) * DIM + 2 * lane];
      float2 w1 = *(const float2*)&Wl[(k + 1) * DIM + 2 * lane];
      float2 w2 = *(const float2*)&Wl[(k + 2) * DIM + 2 * lane];
      float2 w3 = *(const float2*)&Wl[(k + 3) * DIM + 2 * lane];
      c1x = fmaf(u.x, w0.x, c1x); c1y = fmaf(u.x, w0.y, c1y);
      c2x = fmaf(v.x, w0.x, c2x); c2y = fmaf(v.x, w0.y, c2y);
      c1x = fmaf(u.y, w1.x, c1x); c1y = fmaf(u.y, w1.y, c1y);
      c2x = fmaf(v.y, w1.x, c2x); c2y = fmaf(v.y, w1.y, c2y);
      c1x = fmaf(u.z, w2.x, c1x); c1y = fmaf(u.z, w2.y, c1y);
      c2x = fmaf(v.z, w2.x, c2x); c2y = fmaf(v.z, w2.y, c2y);
      c1x = fmaf(u.w, w3.x, c1x); c1y = fmaf(u.w, w3.y, c1y);
      c2x = fmaf(v.w, w3.x, c2x); c2y = fmaf(v.w, w3.y, c2y);
    }
    a1 += tanhf(c1x + b0) * q0 + tanhf(c1y + b1) * q1;
    a2 += tanhf(c2x + b0) * q0 + tanhf(c2y + b1) * q1;
  }
#pragma unroll
  for (int off = 32; off; off >>= 1) {
    a1 += __shfl_down(a1, off, 64);
    a2 += __shfl_down(a2, off, 64);
  }
  __syncthreads();  // done reading Wl; reuse as scratch
  if (lane == 0) { Wl[wid] = a1; Wl[8 + wid] = a2; }
  __syncthreads();
  if (threadIdx.x == 0) {
    float s1 = 0, s2 = 0;
    for (int w = 0; w < 8; ++w) { s1 += Wl[w]; s2 += Wl[8 + w]; }
    atomicAdd(&wsum[0], s1);
    atomicAdd(&wsum[1], s2);
  }
}

// ---------------- x = beta1*z1 + beta2*z2 (in place over z1) ----------------
__global__ void k_combine(float* __restrict__ x, const float* __restrict__ z2,
                          const float* __restrict__ wsum, float invN, int total4) {
  float w1 = wsum[0] * invN, w2 = wsum[1] * invN;
  float mx = fmaxf(w1, w2);
  float e1 = expf(w1 - mx), e2 = expf(w2 - mx);
  float inv = 1.f / (e1 + e2);
  float b1 = e1 * inv, b2 = e2 * inv;
  float4* x4 = (float4*)x;
  const float4* z4 = (const float4*)z2;
  int i = blockIdx.x * blockDim.x + threadIdx.x;
  int st = gridDim.x * blockDim.x;
  for (; i < total4; i += st) {
    float4 a = x4[i], b = z4[i];
    a.x = b1 * a.x + b2 * b.x;
    a.y = b1 * a.y + b2 * b.y;
    a.z = b1 * a.z + b2 * b.z;
    a.w = b1 * a.w + b2 * b.w;
    x4[i] = a;
  }
}

// ---------------- column stats for BOTH outputs ----------------
__global__ __launch_bounds__(128) void k_stats2(const float* __restrict__ xp,
                                                const float* __restrict__ xa,
                                                int NP, int NA, float* __restrict__ st) {
  int d = threadIdx.x;
  float sp = 0, qp = 0, sa = 0, qa = 0;
  for (int n = blockIdx.x; n < NP; n += gridDim.x) {
    float v = xp[(size_t)n * DIM + d]; sp += v; qp += v * v;
  }
  for (int n = blockIdx.x; n < NA; n += gridDim.x) {
    float v = xa[(size_t)n * DIM + d]; sa += v; qa += v * v;
  }
  atomicAdd(&st[d], sp);
  atomicAdd(&st[DIM + d], qp);
  atomicAdd(&st[2 * DIM + d], sa);
  atomicAdd(&st[3 * DIM + d], qa);
}

// ---------------- BatchNorm + row L2 normalize, wave per row, both outputs ----------------
__global__ __launch_bounds__(256) void k_post2(float* __restrict__ xp, float* __restrict__ xa,
                                               const float* __restrict__ st,
                                               const float* __restrict__ gamma,
                                               const float* __restrict__ beta,
                                               int NP, int NA) {
  int lane = threadIdx.x & 63;
  int wv = blockIdx.x * 4 + (threadIdx.x >> 6), nw = gridDim.x * 4;
  int d0 = 2 * lane, d1 = d0 + 1;
  {
    float invN = 1.f / (float)NP;
    float mu0 = st[d0] * invN, mu1 = st[d1] * invN;
    float g0 = gamma[d0] * rsqrtf(st[DIM + d0] * invN - mu0 * mu0 + 1e-5f);
    float g1 = gamma[d1] * rsqrtf(st[DIM + d1] * invN - mu1 * mu1 + 1e-5f);
    float b0 = beta[d0], b1 = beta[d1];
    for (int n = wv; n < NP; n += nw) {
      float2 v = *(float2*)(xp + (size_t)n * DIM + d0);
      float y0 = fmaf(v.x - mu0, g0, b0);
      float y1 = fmaf(v.y - mu1, g1, b1);
      float p = y0 * y0 + y1 * y1;
#pragma unroll
      for (int off = 32; off; off >>= 1) p += __shfl_xor(p, off, 64);
      float r = rsqrtf(p + 1e-12f);
      float2 o; o.x = y0 * r; o.y = y1 * r;
      *(float2*)(xp + (size_t)n * DIM + d0) = o;
    }
  }
  {
    float invN = 1.f / (float)NA;
    float mu0 = st[2 * DIM + d0] * invN, mu1 = st[2 * DIM + d1] * invN;
    float g0 = gamma[d0] * rsqrtf(st[3 * DIM + d0] * invN - mu0 * mu0 + 1e-5f);
    float g1 = gamma[d1] * rsqrtf(st[3 * DIM + d1] * invN - mu1 * mu1 + 1e-5f);
    float b0 = beta[d0], b1 = beta[d1];
    for (int n = wv; n < NA; n += nw) {
      float2 v = *(float2*)(xa + (size_t)n * DIM + d0);
      float y0 = fmaf(v.x - mu0, g0, b0);
      float y1 = fmaf(v.y - mu1, g1, b1);
      float p = y0 * y0 + y1 * y1;
#pragma unroll
      for (int off = 32; off; off >>= 1) p += __shfl_xor(p, off, 64);
      float r = rsqrtf(p + 1e-12f);
      float2 o; o.x = y0 * r; o.y = y1 * r;
      *(float2*)(xa + (size_t)n * DIM + d0) = o;
    }
  }
}

extern "C" void kernel_launch(void* const* d_in, const int* in_sizes, int n_in,
                              void* d_out, int out_size, void* d_ws, size_t ws_size,
                              hipStream_t stream) {
  const float* h_paper  = (const float*)d_in[0];
  const float* h_author = (const float*)d_in[1];
  const float* W_r1 = (const float*)d_in[2];
  const float* W_r2 = (const float*)d_in[3];
  const float* W_r3 = (const float*)d_in[4];
  const float* att_W = (const float*)d_in[5];
  const float* att_b = (const float*)d_in[6];
  const float* att_q = (const float*)d_in[7];
  const float* bn_g = (const float*)d_in[8];
  const float* bn_b = (const float*)d_in[9];
  const int* src_r1 = (const int*)d_in[10];
  const int* dst_r1 = (const int*)d_in[11];
  const int* src_r2 = (const int*)d_in[12];
  const int* dst_r2 = (const int*)d_in[13];
  const int* src_r3 = (const int*)d_in[14];
  const int* dst_r3 = (const int*)d_in[15];

  int NP = in_sizes[0] / DIM;
  int NA = in_sizes[1] / DIM;
  int E1 = in_sizes[10], E2 = in_sizes[12], E3 = in_sizes[14];
  int ET = E1 + E2 + E3;
  int NM = NP > NA ? NP : NA;
  int NB = (NM + 63) >> 6;              // buckets per relation (dst/64)
  int TB = 3 * NB;                      // total buckets
  int M = TB * NBLK;                    // offset-matrix length
  int B = (M + 2047) / 2048;            // scan partial blocks (<=256)

  char* ws = (char*)d_ws;
  size_t off = 0;
  float* m_buf = (float*)(ws + off);    off += align256((size_t)NM * DIM * 4);
  float* z2    = (float*)(ws + off);    off += align256((size_t)NP * DIM * 4);
  unsigned* ebuf = (unsigned*)(ws + off); off += align256((size_t)ET * 4);
  unsigned short* ebuf2 = (unsigned short*)(ws + off); off += align256((size_t)ET * 2);
  int* Hmat    = (int*)(ws + off);      off += align256((size_t)M * 4);
  int* rp      = (int*)(ws + off);      off += align256(((size_t)M + 1) * 4);
  int* rp2     = (int*)(ws + off);      off += align256((size_t)3 * NM * 4);
  int* deg     = (int*)(ws + off);      off += align256((size_t)3 * NM * 4);
  int* part    = (int*)(ws + off);      off += align256(256 * 4);
  size_t zoff = off;  // zero-initialized region
  int* dout    = (int*)(ws + off);      off += (size_t)3 * NM * 4;
  float* wsum  = (float*)(ws + off);    off += 2 * 4;
  float* stats = (float*)(ws + off);    off += 4 * DIM * 4;
  size_t zbytes = off - zoff;

  float* xp = (float*)d_out;                       // papers (z_p1 staging)
  float* xa = (float*)d_out + (size_t)NP * DIM;    // authors (z_a1 staging)

  hipMemsetAsync(ws + zoff, 0, zbytes, stream);

  // out-degrees for GEMM pre-scale
  k_dout<<<2048, 256, 0, stream>>>(src_r1, E1, src_r2, E2, src_r3, E3, dout, NM);

  // bucket partition: histogram -> scan -> scatter -> per-bucket dst sort
  k_hist<<<NBLK, 256, 0, stream>>>(dst_r1, E1, dst_r2, E2, dst_r3, E3, Hmat, NB, TB);
  k_scan1<<<B, 256, 0, stream>>>(Hmat, part, M);
  k_scan2<<<1, 256, 0, stream>>>(part, B, rp, M);
  k_scan3<<<B, 256, 0, stream>>>(Hmat, part, rp, M);
  k_scatter<<<NBLK, 256, 0, stream>>>(src_r1, dst_r1, E1, src_r2, dst_r2, E2,
                                      src_r3, dst_r3, E3, rp, ebuf, NB, TB);
  k_bsort<<<TB, 256, 0, stream>>>(ebuf, rp, ebuf2, rp2, deg, NB, NM);

  // r1: author -> paper (z_p1 -> xp)
  k_gemm<<<512, 512, 0, stream>>>(h_author, W_r1, dout, m_buf, NA);
  k_pull2<<<2048, 256, 0, stream>>>(m_buf, rp2, deg, ebuf2, xp, NP);
  // r2: paper -> paper (z_p2 -> ws)
  k_gemm<<<512, 512, 0, stream>>>(h_paper, W_r2, dout + NM, m_buf, NP);
  k_pull2<<<2048, 256, 0, stream>>>(m_buf, rp2 + NM, deg + NM, ebuf2, z2, NP);
  // r3: author -> author (z_a1 -> xa; softmax over 1 relation == identity)
  k_gemm<<<512, 512, 0, stream>>>(h_author, W_r3, dout + 2 * NM, m_buf, NA);
  k_pull2<<<2048, 256, 0, stream>>>(m_buf, rp2 + 2 * NM, deg + 2 * NM, ebuf2, xa, NA);

  // semantic attention (papers)
  k_att<<<512, 512, 0, stream>>>(xp, z2, att_W, att_b, att_q, wsum, NP);
  k_combine<<<2048, 256, 0, stream>>>(xp, z2, wsum, 1.0f / (float)NP, NP * DIM / 4);

  // BatchNorm stats + apply + row L2 for both outputs
  k_stats2<<<1024, 128, 0, stream>>>(xp, xa, NP, NA, stats);
  k_post2<<<2048, 256, 0, stream>>>(xp, xa, stats, bn_g, bn_b, NP, NA);
}

// Round 12
// 993.407 us; speedup vs baseline: 2.8161x; 1.0215x over previous
//
#include <hip/hip_runtime.h>

#define DIM 128
#define NBLK 64       // partition blocks (first-level)
#define MAXTB 2560    // max total buckets (3 * ceil(50000/64) = 2346)

static inline size_t align256(size_t x) { return (x + 255) & ~(size_t)255; }

// ---------------- out-degree counting (for GEMM pre-scale), all 3 relations ----------------
__global__ void k_dout(const int* __restrict__ s1, int E1,
                       const int* __restrict__ s2, int E2,
                       const int* __restrict__ s3, int E3,
                       int* __restrict__ dout, int NM) {
  int i = blockIdx.x * blockDim.x + threadIdx.x;
  int st = gridDim.x * blockDim.x;
  int ET = E1 + E2 + E3;
  for (; i < ET; i += st) {
    const int* sp; int j, r;
    if (i < E1) { r = 0; j = i; sp = s1; }
    else if (i < E1 + E2) { r = 1; j = i - E1; sp = s2; }
    else { r = 2; j = i - E1 - E2; sp = s3; }
    atomicAdd(&dout[r * NM + sp[j]], 1);
  }
}

// ---------------- per-(bucket,block) histogram ----------------
__global__ __launch_bounds__(256) void k_hist(const int* __restrict__ d1, int E1,
                                              const int* __restrict__ d2, int E2,
                                              const int* __restrict__ d3, int E3,
                                              int* __restrict__ Hmat, int NB, int TB) {
  __shared__ int hl[MAXTB];
  int t = threadIdx.x, b = blockIdx.x;
  for (int k = t; k < TB; k += 256) hl[k] = 0;
  __syncthreads();
  int ET = E1 + E2 + E3;
  int CH = (ET + NBLK - 1) / NBLK;
  int lo = b * CH, hi = min(lo + CH, ET);
  for (int i = lo + t; i < hi; i += 256) {
    const int* dp; int j, r;
    if (i < E1) { r = 0; j = i; dp = d1; }
    else if (i < E1 + E2) { r = 1; j = i - E1; dp = d2; }
    else { r = 2; j = i - E1 - E2; dp = d3; }
    int kb = r * NB + (dp[j] >> 6);
    atomicAdd(&hl[kb], 1);
  }
  __syncthreads();
  for (int k = t; k < TB; k += 256) Hmat[(size_t)k * NBLK + b] = hl[k];
}

// ---------------- multi-block scan (bucket-major matrix) ----------------
__global__ __launch_bounds__(256) void k_scan1(const int* __restrict__ cnt,
                                               int* __restrict__ part, int M) {
  __shared__ int wsh[4];
  int t = threadIdx.x;
  int base = blockIdx.x * 2048 + t * 8;
  int s = 0;
  if (base + 8 <= M) {
    const int4* p = (const int4*)(cnt + base);
    int4 a = p[0], b = p[1];
    s = a.x + a.y + a.z + a.w + b.x + b.y + b.z + b.w;
  } else {
    for (int j = 0; j < 8; ++j) { int idx = base + j; if (idx < M) s += cnt[idx]; }
  }
#pragma unroll
  for (int off = 32; off; off >>= 1) s += __shfl_down(s, off, 64);
  int lane = t & 63, wid = t >> 6;
  if (lane == 0) wsh[wid] = s;
  __syncthreads();
  if (t == 0) part[blockIdx.x] = wsh[0] + wsh[1] + wsh[2] + wsh[3];
}

__global__ __launch_bounds__(256) void k_scan2(int* __restrict__ part, int B,
                                               int* __restrict__ rp, int M) {
  __shared__ int sh[256];
  int t = threadIdx.x;
  sh[t] = (t < B) ? part[t] : 0;
  __syncthreads();
  for (int off = 1; off < 256; off <<= 1) {
    int v = (t >= off) ? sh[t - off] : 0;
    __syncthreads();
    sh[t] += v;
    __syncthreads();
  }
  if (t < B) part[t] = t ? sh[t - 1] : 0;
  if (t == 0) rp[M] = sh[255];
}

__global__ __launch_bounds__(256) void k_scan3(const int* __restrict__ cnt,
                                               const int* __restrict__ part,
                                               int* __restrict__ rp, int M) {
  __shared__ int wsh[4];
  int t = threadIdx.x, lane = t & 63, wid = t >> 6;
  int base = blockIdx.x * 2048 + t * 8;
  int v[8];
  if (base + 8 <= M) {
    const int4* p = (const int4*)(cnt + base);
    int4 a = p[0], b = p[1];
    v[0] = a.x; v[1] = a.y; v[2] = a.z; v[3] = a.w;
    v[4] = b.x; v[5] = b.y; v[6] = b.z; v[7] = b.w;
  } else {
    for (int j = 0; j < 8; ++j) { int idx = base + j; v[j] = (idx < M) ? cnt[idx] : 0; }
  }
  int ts = 0;
#pragma unroll
  for (int j = 0; j < 8; ++j) ts += v[j];
  int incl = ts;
#pragma unroll
  for (int d = 1; d < 64; d <<= 1) { int u = __shfl_up(incl, d, 64); if (lane >= d) incl += u; }
  if (lane == 63) wsh[wid] = incl;
  __syncthreads();
  int woff = 0;
  for (int w = 0; w < wid; ++w) woff += wsh[w];
  int run = part[blockIdx.x] + woff + incl - ts;
#pragma unroll
  for (int j = 0; j < 8; ++j) {
    int idx = base + j;
    if (idx < M) rp[idx] = run;
    run += v[j];
  }
}

// ---------------- scatter edges into bucket-grouped buffer (LDS cursors) ----------------
__global__ __launch_bounds__(256) void k_scatter(const int* __restrict__ s1, const int* __restrict__ d1, int E1,
                                                 const int* __restrict__ s2, const int* __restrict__ d2, int E2,
                                                 const int* __restrict__ s3, const int* __restrict__ d3, int E3,
                                                 const int* __restrict__ rp,
                                                 unsigned* __restrict__ ebuf, int NB, int TB) {
  __shared__ int curl[MAXTB];
  int t = threadIdx.x, b = blockIdx.x;
  for (int k = t; k < TB; k += 256) curl[k] = rp[(size_t)k * NBLK + b];
  __syncthreads();
  int ET = E1 + E2 + E3;
  int CH = (ET + NBLK - 1) / NBLK;
  int lo = b * CH, hi = min(lo + CH, ET);
  for (int i = lo + t; i < hi; i += 256) {
    const int* sp; const int* dp; int j, r;
    if (i < E1) { r = 0; j = i; sp = s1; dp = d1; }
    else if (i < E1 + E2) { r = 1; j = i - E1; sp = s2; dp = d2; }
    else { r = 2; j = i - E1 - E2; sp = s3; dp = d3; }
    int dst = dp[j];
    int kb = r * NB + (dst >> 6);
    int pos = atomicAdd(&curl[kb], 1);
    ebuf[pos] = ((unsigned)(dst & 63) << 16) | (unsigned)sp[j];
  }
}

// ---------------- second level: sort each bucket by dst, emit per-dst CSR ----------------
__global__ __launch_bounds__(256) void k_bsort(const unsigned* __restrict__ ebuf,
                                               const int* __restrict__ rp,
                                               unsigned short* __restrict__ ebuf2,
                                               int* __restrict__ rp2, int* __restrict__ deg,
                                               int NB, int NM) {
  __shared__ int hist[64];
  __shared__ int cursor[64];
  int t = threadIdx.x;
  int k = blockIdx.x;
  if (t < 64) hist[t] = 0;
  __syncthreads();
  int start = rp[(size_t)k * NBLK];
  int end = rp[(size_t)(k + 1) * NBLK];
  for (int e = start + t; e < end; e += 256)
    atomicAdd(&hist[ebuf[e] >> 16], 1);
  __syncthreads();
  if (t < 64) {
    int v = hist[t];
    int incl = v;
#pragma unroll
    for (int d = 1; d < 64; d <<= 1) { int u = __shfl_up(incl, d, 64); if (t >= d) incl += u; }
    int excl = incl - v;
    cursor[t] = start + excl;
    int r = k / NB, bb = k - r * NB;
    int ld = bb * 64 + t;
    if (ld < NM) {
      rp2[r * NM + ld] = start + excl;
      deg[r * NM + ld] = v;
    }
  }
  __syncthreads();
  for (int e = start + t; e < end; e += 256) {
    unsigned p = ebuf[e];
    int pos = atomicAdd(&cursor[p >> 16], 1);
    ebuf2[pos] = (unsigned short)(p & 0xFFFF);
  }
}

// ---------------- pull aggregation (2 rows per wave, float4 gathers) ----------------
__global__ __launch_bounds__(256) void k_pull2(const float* __restrict__ m,
                                               const int* __restrict__ rp2,
                                               const int* __restrict__ deg,
                                               const unsigned short* __restrict__ ebuf2,
                                               float* __restrict__ z, int N) {
  int lane = threadIdx.x & 63, wid = threadIdx.x >> 6;
  int half = lane >> 5, hl = lane & 31;
  int gw = blockIdx.x * 4 + wid, nw = gridDim.x * 4;
  for (int n0 = gw * 2; n0 < N; n0 += nw * 2) {
    int n = n0 + half;
    bool valid = n < N;
    int b = 0, d = 0;
    if (valid) { b = rp2[n]; d = deg[n]; }
    float ax = 0.f, ay = 0.f, az = 0.f, aw = 0.f;
    for (int i = 0; i < d; ++i) {
      int s = ebuf2[b + i];
      float4 v = *(const float4*)(m + (size_t)s * DIM + hl * 4);
      ax += v.x; ay += v.y; az += v.z; aw += v.w;
    }
    if (valid) {
      float sc = rsqrtf(fmaxf((float)d, 1.0f));
      float4 o; o.x = ax * sc; o.y = ay * sc; o.z = az * sc; o.w = aw * sc;
      *(float4*)(z + (size_t)n * DIM + hl * 4) = o;
    }
  }
}

// ---------------- m = (h * rsqrt(deg)) @ W  (wave handles 4 nodes per Wl pass) ----------------
__global__ __launch_bounds__(512) void k_gemm(const float* __restrict__ h,
                                              const float* __restrict__ W,
                                              const int* __restrict__ degout,
                                              float* __restrict__ m, int N) {
  __shared__ float Wl[DIM * DIM];
  for (int i = threadIdx.x; i < DIM * DIM; i += 512) Wl[i] = W[i];
  __syncthreads();
  int lane = threadIdx.x & 63, wid = threadIdx.x >> 6;
  int gw = blockIdx.x * 8 + wid, nw = gridDim.x * 8;
  for (int n0 = gw * 4; n0 < N; n0 += nw * 4) {
    int nc1 = min(n0 + 1, N - 1), nc2 = min(n0 + 2, N - 1), nc3 = min(n0 + 3, N - 1);
    const float4* h0 = (const float4*)(h + (size_t)n0 * DIM);
    const float4* h1 = (const float4*)(h + (size_t)nc1 * DIM);
    const float4* h2 = (const float4*)(h + (size_t)nc2 * DIM);
    const float4* h3 = (const float4*)(h + (size_t)nc3 * DIM);
    float ax0 = 0, ay0 = 0, ax1 = 0, ay1 = 0, ax2 = 0, ay2 = 0, ax3 = 0, ay3 = 0;
#pragma unroll 2
    for (int k4 = 0; k4 < 32; ++k4) {
      float4 u0 = h0[k4], u1 = h1[k4], u2 = h2[k4], u3 = h3[k4];
      int k = k4 * 4;
      float2 w0 = *(const float2*)&Wl[(k + 0) * DIM + 2 * lane];
      float2 w1 = *(const float2*)&Wl[(k + 1) * DIM + 2 * lane];
      float2 w2 = *(const float2*)&Wl[(k + 2) * DIM + 2 * lane];
      float2 w3 = *(const float2*)&Wl[(k + 3) * DIM + 2 * lane];
      ax0 = fmaf(u0.x, w0.x, ax0); ay0 = fmaf(u0.x, w0.y, ay0);
      ax1 = fmaf(u1.x, w0.x, ax1); ay1 = fmaf(u1.x, w0.y, ay1);
      ax2 = fmaf(u2.x, w0.x, ax2); ay2 = fmaf(u2.x, w0.y, ay2);
      ax3 = fmaf(u3.x, w0.x, ax3); ay3 = fmaf(u3.x, w0.y, ay3);
      ax0 = fmaf(u0.y, w1.x, ax0); ay0 = fmaf(u0.y, w1.y, ay0);
      ax1 = fmaf(u1.y, w1.x, ax1); ay1 = fmaf(u1.y, w1.y, ay1);
      ax2 = fmaf(u2.y, w1.x, ax2); ay2 = fmaf(u2.y, w1.y, ay2);
      ax3 = fmaf(u3.y, w1.x, ax3); ay3 = fmaf(u3.y, w1.y, ay3);
      ax0 = fmaf(u0.z, w2.x, ax0); ay0 = fmaf(u0.z, w2.y, ay0);
      ax1 = fmaf(u1.z, w2.x, ax1); ay1 = fmaf(u1.z, w2.y, ay1);
      ax2 = fmaf(u2.z, w2.x, ax2); ay2 = fmaf(u2.z, w2.y, ay2);
      ax3 = fmaf(u3.z, w2.x, ax3); ay3 = fmaf(u3.z, w2.y, ay3);
      ax0 = fmaf(u0.w, w3.x, ax0); ay0 = fmaf(u0.w, w3.y, ay0);
      ax1 = fmaf(u1.w, w3.x, ax1); ay1 = fmaf(u1.w, w3.y, ay1);
      ax2 = fmaf(u2.w, w3.x, ax2); ay2 = fmaf(u2.w, w3.y, ay2);
      ax3 = fmaf(u3.w, w3.x, ax3); ay3 = fmaf(u3.w, w3.y, ay3);
    }
    float s0 = rsqrtf(fmaxf((float)degout[n0], 1.0f));
    float2 o0; o0.x = s0 * ax0; o0.y = s0 * ay0;
    *(float2*)(m + (size_t)n0 * DIM + 2 * lane) = o0;
    if (n0 + 1 < N) {
      float s = rsqrtf(fmaxf((float)degout[n0 + 1], 1.0f));
      float2 o; o.x = s * ax1; o.y = s * ay1;
      *(float2*)(m + (size_t)(n0 + 1) * DIM + 2 * lane) = o;
    }
    if (n0 + 2 < N) {
      float s = rsqrtf(fmaxf((float)degout[n0 + 2], 1.0f));
      float2 o; o.x = s * ax2; o.y = s * ay2;
      *(float2*)(m + (size_t)(n0 + 2) * DIM + 2 * lane) = o;
    }
    if (n0 + 3 < N) {
      float s = rsqrtf(fmaxf((float)degout[n0 + 3], 1.0f));
      float2 o; o.x = s * ax3; o.y = s * ay3;
      *(float2*)(m + (size_t)(n0 + 3) * DIM + 2 * lane) = o;
    }
  }
}

// ---------------- attention scores (wave handles 4 rows per Wl pass) ----------------
__global__ __launch_bounds__(512) void k_att(const float* __restrict__ z1,
                                             const float* __restrict__ z2,
                                             const float* __restrict__ attW,
                                             const float* __restrict__ attb,
                                             const float* __restrict__ attq,
                                             float* __restrict__ wsum, int N) {
  __shared__ float Wl[DIM * DIM];
  for (int i = threadIdx.x; i < DIM * DIM; i += 512) Wl[i] = attW[i];
  int lane = threadIdx.x & 63, wid = threadIdx.x >> 6;
  float b0 = attb[2 * lane], b1 = attb[2 * lane + 1];
  float q0 = attq[2 * lane], q1 = attq[2 * lane + 1];
  __syncthreads();
  int gw = blockIdx.x * 8 + wid, nw = gridDim.x * 8;
  float a1 = 0.f, a2 = 0.f;
  for (int n0 = gw * 4; n0 < N; n0 += nw * 4) {
    int nc1 = min(n0 + 1, N - 1), nc2 = min(n0 + 2, N - 1), nc3 = min(n0 + 3, N - 1);
    const float4* p0 = (const float4*)(z1 + (size_t)n0 * DIM);
    const float4* p1 = (const float4*)(z1 + (size_t)nc1 * DIM);
    const float4* p2 = (const float4*)(z1 + (size_t)nc2 * DIM);
    const float4* p3 = (const float4*)(z1 + (size_t)nc3 * DIM);
    const float4* r0 = (const float4*)(z2 + (size_t)n0 * DIM);
    const float4* r1 = (const float4*)(z2 + (size_t)nc1 * DIM);
    const float4* r2 = (const float4*)(z2 + (size_t)nc2 * DIM);
    const float4* r3 = (const float4*)(z2 + (size_t)nc3 * DIM);
    float cx[4] = {0, 0, 0, 0}, cy[4] = {0, 0, 0, 0};
    float dx[4] = {0, 0, 0, 0}, dy[4] = {0, 0, 0, 0};
#pragma unroll 2
    for (int k4 = 0; k4 < 32; ++k4) {
      float4 u0 = p0[k4], u1 = p1[k4], u2 = p2[k4], u3 = p3[k4];
      float4 v0 = r0[k4], v1 = r1[k4], v2 = r2[k4], v3 = r3[k4];
      int k = k4 * 4;
      float2 w0 = *(const float2*)&Wl[(k + 0) * DIM + 2 * lane];
      float2 w1 = *(const float2*)&Wl[(k + 1) * DIM + 2 * lane];
      float2 w2 = *(const float2*)&Wl[(k + 2) * DIM + 2 * lane];
      float2 w3 = *(const float2*)&Wl[(k + 3) * DIM + 2 * lane];
      cx[0] = fmaf(u0.x, w0.x, cx[0]); cy[0] = fmaf(u0.x, w0.y, cy[0]);
      cx[1] = fmaf(u1.x, w0.x, cx[1]); cy[1] = fmaf(u1.x, w0.y, cy[1]);
      cx[2] = fmaf(u2.x, w0.x, cx[2]); cy[2] = fmaf(u2.x, w0.y, cy[2]);
      cx[3] = fmaf(u3.x, w0.x, cx[3]); cy[3] = fmaf(u3.x, w0.y, cy[3]);
      dx[0] = fmaf(v0.x, w0.x, dx[0]); dy[0] = fmaf(v0.x, w0.y, dy[0]);
      dx[1] = fmaf(v1.x, w0.x, dx[1]); dy[1] = fmaf(v1.x, w0.y, dy[1]);
      dx[2] = fmaf(v2.x, w0.x, dx[2]); dy[2] = fmaf(v2.x, w0.y, dy[2]);
      dx[3] = fmaf(v3.x, w0.x, dx[3]); dy[3] = fmaf(v3.x, w0.y, dy[3]);
      cx[0] = fmaf(u0.y, w1.x, cx[0]); cy[0] = fmaf(u0.y, w1.y, cy[0]);
      cx[1] = fmaf(u1.y, w1.x, cx[1]); cy[1] = fmaf(u1.y, w1.y, cy[1]);
      cx[2] = fmaf(u2.y, w1.x, cx[2]); cy[2] = fmaf(u2.y, w1.y, cy[2]);
      cx[3] = fmaf(u3.y, w1.x, cx[3]); cy[3] = fmaf(u3.y, w1.y, cy[3]);
      dx[0] = fmaf(v0.y, w1.x, dx[0]); dy[0] = fmaf(v0.y, w1.y, dy[0]);
      dx[1] = fmaf(v1.y, w1.x, dx[1]); dy[1] = fmaf(v1.y, w1.y, dy[1]);
      dx[2] = fmaf(v2.y, w1.x, dx[2]); dy[2] = fmaf(v2.y, w1.y, dy[2]);
      dx[3] = fmaf(v3.y, w1.x, dx[3]); dy[3] = fmaf(v3.y, w1.y, dy[3]);
      cx[0] = fmaf(u0.z, w2.x, cx[0]); cy[0] = fmaf(u0.z, w2.y, cy[0]);
      cx[1] = fmaf(u1.z, w2.x, cx[1]); cy[1] = fmaf(u1.z, w2.y, cy[1]);
      cx[2] = fmaf(u2.z, w2.x, cx[2]); cy[2] = fmaf(u2.z, w2.y, cy[2]);
      cx[3] = fmaf(u3.z, w2.x, cx[3]); cy[3] = fmaf(u3.z, w2.y, cy[3]);
      dx[0] = fmaf(v0.z, w2.x, dx[0]); dy[0] = fmaf(v0.z, w2.y, dy[0]);
      dx[1] = fmaf(v1.z, w2.x, dx[1]); dy[1] = fmaf(v1.z, w2.y, dy[1]);
      dx[2] = fmaf(v2.z, w2.x, dx[2]); dy[2] = fmaf(v2.z, w2.y, dy[2]);
      dx[3] = fmaf(v3.z, w2.x, dx[3]); dy[3] = fmaf(v3.z, w2.y, dy[3]);
      cx[0] = fmaf(u0.w, w3.x, cx[0]); cy[0] = fmaf(u0.w, w3.y, cy[0]);
      cx[1] = fmaf(u1.w, w3.x, cx[1]); cy[1] = fmaf(u1.w, w3.y, cy[1]);
      cx[2] = fmaf(u2.w, w3.x, cx[2]); cy[2] = fmaf(u2.w, w3.y, cy[2]);
      cx[3] = fmaf(u3.w, w3.x, cx[3]); cy[3] = fmaf(u3.w, w3.y, cy[3]);
      dx[0] = fmaf(v0.w, w3.x, dx[0]); dy[0] = fmaf(v0.w, w3.y, dy[0]);
      dx[1] = fmaf(v1.w, w3.x, dx[1]); dy[1] = fmaf(v1.w, w3.y, dy[1]);
      dx[2] = fmaf(v2.w, w3.x, dx[2]); dy[2] = fmaf(v2.w, w3.y, dy[2]);
      dx[3] = fmaf(v3.w, w3.x, dx[3]); dy[3] = fmaf(v3.w, w3.y, dy[3]);
    }
    int nv = N - n0;
#pragma unroll
    for (int j = 0; j < 4; ++j) {
      if (j < nv) {
        a1 += tanhf(cx[j] + b0) * q0 + tanhf(cy[j] + b1) * q1;
        a2 += tanhf(dx[j] + b0) * q0 + tanhf(dy[j] + b1) * q1;
      }
    }
  }
#pragma unroll
  for (int off = 32; off; off >>= 1) {
    a1 += __shfl_down(a1, off, 64);
    a2 += __shfl_down(a2, off, 64);
  }
  __syncthreads();  // done reading Wl; reuse as scratch
  if (lane == 0) { Wl[wid] = a1; Wl[8 + wid] = a2; }
  __syncthreads();
  if (threadIdx.x == 0) {
    float s1 = 0, s2 = 0;
    for (int w = 0; w < 8; ++w) { s1 += Wl[w]; s2 += Wl[8 + w]; }
    atomicAdd(&wsum[0], s1);
    atomicAdd(&wsum[1], s2);
  }
}

// ---------------- x = beta1*z1 + beta2*z2 (in place over z1) ----------------
__global__ void k_combine(float* __restrict__ x, const float* __restrict__ z2,
                          const float* __restrict__ wsum, float invN, int total4) {
  float w1 = wsum[0] * invN, w2 = wsum[1] * invN;
  float mx = fmaxf(w1, w2);
  float e1 = expf(w1 - mx), e2 = expf(w2 - mx);
  float inv = 1.f / (e1 + e2);
  float b1 = e1 * inv, b2 = e2 * inv;
  float4* x4 = (float4*)x;
  const float4* z4 = (const float4*)z2;
  int i = blockIdx.x * blockDim.x + threadIdx.x;
  int st = gridDim.x * blockDim.x;
  for (; i < total4; i += st) {
    float4 a = x4[i], b = z4[i];
    a.x = b1 * a.x + b2 * b.x;
    a.y = b1 * a.y + b2 * b.y;
    a.z = b1 * a.z + b2 * b.z;
    a.w = b1 * a.w + b2 * b.w;
    x4[i] = a;
  }
}

// ---------------- column stats for BOTH outputs ----------------
__global__ __launch_bounds__(128) void k_stats2(const float* __restrict__ xp,
                                                const float* __restrict__ xa,
                                                int NP, int NA, float* __restrict__ st) {
  int d = threadIdx.x;
  float sp = 0, qp = 0, sa = 0, qa = 0;
  for (int n = blockIdx.x; n < NP; n += gridDim.x) {
    float v = xp[(size_t)n * DIM + d]; sp += v; qp += v * v;
  }
  for (int n = blockIdx.x; n < NA; n += gridDim.x) {
    float v = xa[(size_t)n * DIM + d]; sa += v; qa += v * v;
  }
  atomicAdd(&st[d], sp);
  atomicAdd(&st[DIM + d], qp);
  atomicAdd(&st[2 * DIM + d], sa);
  atomicAdd(&st[3 * DIM + d], qa);
}

// ---------------- BatchNorm + row L2 normalize, wave per row, both outputs ----------------
__global__ __launch_bounds__(256) void k_post2(float* __restrict__ xp, float* __restrict__ xa,
                                               const float* __restrict__ st,
                                               const float* __restrict__ gamma,
                                               const float* __restrict__ beta,
                                               int NP, int NA) {
  int lane = threadIdx.x & 63;
  int wv = blockIdx.x * 4 + (threadIdx.x >> 6), nw = gridDim.x * 4;
  int d0 = 2 * lane, d1 = d0 + 1;
  {
    float invN = 1.f / (float)NP;
    float mu0 = st[d0] * invN, mu1 = st[d1] * invN;
    float g0 = gamma[d0] * rsqrtf(st[DIM + d0] * invN - mu0 * mu0 + 1e-5f);
    float g1 = gamma[d1] * rsqrtf(st[DIM + d1] * invN - mu1 * mu1 + 1e-5f);
    float b0 = beta[d0], b1 = beta[d1];
    for (int n = wv; n < NP; n += nw) {
      float2 v = *(float2*)(xp + (size_t)n * DIM + d0);
      float y0 = fmaf(v.x - mu0, g0, b0);
      float y1 = fmaf(v.y - mu1, g1, b1);
      float p = y0 * y0 + y1 * y1;
#pragma unroll
      for (int off = 32; off; off >>= 1) p += __shfl_xor(p, off, 64);
      float r = rsqrtf(p + 1e-12f);
      float2 o; o.x = y0 * r; o.y = y1 * r;
      *(float2*)(xp + (size_t)n * DIM + d0) = o;
    }
  }
  {
    float invN = 1.f / (float)NA;
    float mu0 = st[2 * DIM + d0] * invN, mu1 = st[2 * DIM + d1] * invN;
    float g0 = gamma[d0] * rsqrtf(st[3 * DIM + d0] * invN - mu0 * mu0 + 1e-5f);
    float g1 = gamma[d1] * rsqrtf(st[3 * DIM + d1] * invN - mu1 * mu1 + 1e-5f);
    float b0 = beta[d0], b1 = beta[d1];
    for (int n = wv; n < NA; n += nw) {
      float2 v = *(float2*)(xa + (size_t)n * DIM + d0);
      float y0 = fmaf(v.x - mu0, g0, b0);
      float y1 = fmaf(v.y - mu1, g1, b1);
      float p = y0 * y0 + y1 * y1;
#pragma unroll
      for (int off = 32; off; off >>= 1) p += __shfl_xor(p, off, 64);
      float r = rsqrtf(p + 1e-12f);
      float2 o; o.x = y0 * r; o.y = y1 * r;
      *(float2*)(xa + (size_t)n * DIM + d0) = o;
    }
  }
}

extern "C" void kernel_launch(void* const* d_in, const int* in_sizes, int n_in,
                              void* d_out, int out_size, void* d_ws, size_t ws_size,
                              hipStream_t stream) {
  const float* h_paper  = (const float*)d_in[0];
  const float* h_author = (const float*)d_in[1];
  const float* W_r1 = (const float*)d_in[2];
  const float* W_r2 = (const float*)d_in[3];
  const float* W_r3 = (const float*)d_in[4];
  const float* att_W = (const float*)d_in[5];
  const float* att_b = (const float*)d_in[6];
  const float* att_q = (const float*)d_in[7];
  const float* bn_g = (const float*)d_in[8];
  const float* bn_b = (const float*)d_in[9];
  const int* src_r1 = (const int*)d_in[10];
  const int* dst_r1 = (const int*)d_in[11];
  const int* src_r2 = (const int*)d_in[12];
  const int* dst_r2 = (const int*)d_in[13];
  const int* src_r3 = (const int*)d_in[14];
  const int* dst_r3 = (const int*)d_in[15];

  int NP = in_sizes[0] / DIM;
  int NA = in_sizes[1] / DIM;
  int E1 = in_sizes[10], E2 = in_sizes[12], E3 = in_sizes[14];
  int ET = E1 + E2 + E3;
  int NM = NP > NA ? NP : NA;
  int NB = (NM + 63) >> 6;              // buckets per relation (dst/64)
  int TB = 3 * NB;                      // total buckets
  int M = TB * NBLK;                    // offset-matrix length
  int B = (M + 2047) / 2048;            // scan partial blocks (<=256)

  char* ws = (char*)d_ws;
  size_t off = 0;
  float* m_buf = (float*)(ws + off);    off += align256((size_t)NM * DIM * 4);
  float* z2    = (float*)(ws + off);    off += align256((size_t)NP * DIM * 4);
  unsigned* ebuf = (unsigned*)(ws + off); off += align256((size_t)ET * 4);
  unsigned short* ebuf2 = (unsigned short*)(ws + off); off += align256((size_t)ET * 2);
  int* Hmat    = (int*)(ws + off);      off += align256((size_t)M * 4);
  int* rp      = (int*)(ws + off);      off += align256(((size_t)M + 1) * 4);
  int* rp2     = (int*)(ws + off);      off += align256((size_t)3 * NM * 4);
  int* deg     = (int*)(ws + off);      off += align256((size_t)3 * NM * 4);
  int* part    = (int*)(ws + off);      off += align256(256 * 4);
  size_t zoff = off;  // zero-initialized region
  int* dout    = (int*)(ws + off);      off += (size_t)3 * NM * 4;
  float* wsum  = (float*)(ws + off);    off += 2 * 4;
  float* stats = (float*)(ws + off);    off += 4 * DIM * 4;
  size_t zbytes = off - zoff;

  float* xp = (float*)d_out;                       // papers (z_p1 staging)
  float* xa = (float*)d_out + (size_t)NP * DIM;    // authors (z_a1 staging)

  hipMemsetAsync(ws + zoff, 0, zbytes, stream);

  // out-degrees for GEMM pre-scale
  k_dout<<<2048, 256, 0, stream>>>(src_r1, E1, src_r2, E2, src_r3, E3, dout, NM);

  // bucket partition: histogram -> scan -> scatter -> per-bucket dst sort
  k_hist<<<NBLK, 256, 0, stream>>>(dst_r1, E1, dst_r2, E2, dst_r3, E3, Hmat, NB, TB);
  k_scan1<<<B, 256, 0, stream>>>(Hmat, part, M);
  k_scan2<<<1, 256, 0, stream>>>(part, B, rp, M);
  k_scan3<<<B, 256, 0, stream>>>(Hmat, part, rp, M);
  k_scatter<<<NBLK, 256, 0, stream>>>(src_r1, dst_r1, E1, src_r2, dst_r2, E2,
                                      src_r3, dst_r3, E3, rp, ebuf, NB, TB);
  k_bsort<<<TB, 256, 0, stream>>>(ebuf, rp, ebuf2, rp2, deg, NB, NM);

  // r1: author -> paper (z_p1 -> xp)
  k_gemm<<<512, 512, 0, stream>>>(h_author, W_r1, dout, m_buf, NA);
  k_pull2<<<2048, 256, 0, stream>>>(m_buf, rp2, deg, ebuf2, xp, NP);
  // r2: paper -> paper (z_p2 -> ws)
  k_gemm<<<512, 512, 0, stream>>>(h_paper, W_r2, dout + NM, m_buf, NP);
  k_pull2<<<2048, 256, 0, stream>>>(m_buf, rp2 + NM, deg + NM, ebuf2, z2, NP);
  // r3: author -> author (z_a1 -> xa; softmax over 1 relation == identity)
  k_gemm<<<512, 512, 0, stream>>>(h_author, W_r3, dout + 2 * NM, m_buf, NA);
  k_pull2<<<2048, 256, 0, stream>>>(m_buf, rp2 + 2 * NM, deg + 2 * NM, ebuf2, xa, NA);

  // semantic attention (papers)
  k_att<<<512, 512, 0, stream>>>(xp, z2, att_W, att_b, att_q, wsum, NP);
  k_combine<<<2048, 256, 0, stream>>>(xp, z2, wsum, 1.0f / (float)NP, NP * DIM / 4);

  // BatchNorm stats + apply + row L2 for both outputs
  k_stats2<<<1024, 128, 0, stream>>>(xp, xa, NP, NA, stats);
  k_post2<<<2048, 256, 0, stream>>>(xp, xa, stats, bn_g, bn_b, NP, NA);
}

// Round 13
// 923.454 us; speedup vs baseline: 3.0294x; 1.0758x over previous
//
#include <hip/hip_runtime.h>

#define DIM 128
#define NBLK 64       // partition blocks (first-level)
#define MAXTB 2560    // max total buckets (3 * ceil(50000/64) = 2346)

static inline size_t align256(size_t x) { return (x + 255) & ~(size_t)255; }

__device__ __forceinline__ unsigned pack2_bf16(float a, float b) {
  unsigned ua = __float_as_uint(a);
  unsigned ub = __float_as_uint(b);
  ua += 0x7FFFu + ((ua >> 16) & 1u);   // round-to-nearest-even
  ub += 0x7FFFu + ((ub >> 16) & 1u);
  return (ua >> 16) | (ub & 0xFFFF0000u);
}

// ---------------- out-degree counting (for GEMM pre-scale), all 3 relations ----------------
__global__ void k_dout(const int* __restrict__ s1, int E1,
                       const int* __restrict__ s2, int E2,
                       const int* __restrict__ s3, int E3,
                       int* __restrict__ dout, int NM) {
  int i = blockIdx.x * blockDim.x + threadIdx.x;
  int st = gridDim.x * blockDim.x;
  int ET = E1 + E2 + E3;
  for (; i < ET; i += st) {
    const int* sp; int j, r;
    if (i < E1) { r = 0; j = i; sp = s1; }
    else if (i < E1 + E2) { r = 1; j = i - E1; sp = s2; }
    else { r = 2; j = i - E1 - E2; sp = s3; }
    atomicAdd(&dout[r * NM + sp[j]], 1);
  }
}

// ---------------- per-(bucket,block) histogram ----------------
__global__ __launch_bounds__(256) void k_hist(const int* __restrict__ d1, int E1,
                                              const int* __restrict__ d2, int E2,
                                              const int* __restrict__ d3, int E3,
                                              int* __restrict__ Hmat, int NB, int TB) {
  __shared__ int hl[MAXTB];
  int t = threadIdx.x, b = blockIdx.x;
  for (int k = t; k < TB; k += 256) hl[k] = 0;
  __syncthreads();
  int ET = E1 + E2 + E3;
  int CH = (ET + NBLK - 1) / NBLK;
  int lo = b * CH, hi = min(lo + CH, ET);
  for (int i = lo + t; i < hi; i += 256) {
    const int* dp; int j, r;
    if (i < E1) { r = 0; j = i; dp = d1; }
    else if (i < E1 + E2) { r = 1; j = i - E1; dp = d2; }
    else { r = 2; j = i - E1 - E2; dp = d3; }
    int kb = r * NB + (dp[j] >> 6);
    atomicAdd(&hl[kb], 1);
  }
  __syncthreads();
  for (int k = t; k < TB; k += 256) Hmat[(size_t)k * NBLK + b] = hl[k];
}

// ---------------- multi-block scan (bucket-major matrix) ----------------
__global__ __launch_bounds__(256) void k_scan1(const int* __restrict__ cnt,
                                               int* __restrict__ part, int M) {
  __shared__ int wsh[4];
  int t = threadIdx.x;
  int base = blockIdx.x * 2048 + t * 8;
  int s = 0;
  if (base + 8 <= M) {
    const int4* p = (const int4*)(cnt + base);
    int4 a = p[0], b = p[1];
    s = a.x + a.y + a.z + a.w + b.x + b.y + b.z + b.w;
  } else {
    for (int j = 0; j < 8; ++j) { int idx = base + j; if (idx < M) s += cnt[idx]; }
  }
#pragma unroll
  for (int off = 32; off; off >>= 1) s += __shfl_down(s, off, 64);
  int lane = t & 63, wid = t >> 6;
  if (lane == 0) wsh[wid] = s;
  __syncthreads();
  if (t == 0) part[blockIdx.x] = wsh[0] + wsh[1] + wsh[2] + wsh[3];
}

__global__ __launch_bounds__(256) void k_scan2(int* __restrict__ part, int B,
                                               int* __restrict__ rp, int M) {
  __shared__ int sh[256];
  int t = threadIdx.x;
  sh[t] = (t < B) ? part[t] : 0;
  __syncthreads();
  for (int off = 1; off < 256; off <<= 1) {
    int v = (t >= off) ? sh[t - off] : 0;
    __syncthreads();
    sh[t] += v;
    __syncthreads();
  }
  if (t < B) part[t] = t ? sh[t - 1] : 0;
  if (t == 0) rp[M] = sh[255];
}

__global__ __launch_bounds__(256) void k_scan3(const int* __restrict__ cnt,
                                               const int* __restrict__ part,
                                               int* __restrict__ rp, int M) {
  __shared__ int wsh[4];
  int t = threadIdx.x, lane = t & 63, wid = t >> 6;
  int base = blockIdx.x * 2048 + t * 8;
  int v[8];
  if (base + 8 <= M) {
    const int4* p = (const int4*)(cnt + base);
    int4 a = p[0], b = p[1];
    v[0] = a.x; v[1] = a.y; v[2] = a.z; v[3] = a.w;
    v[4] = b.x; v[5] = b.y; v[6] = b.z; v[7] = b.w;
  } else {
    for (int j = 0; j < 8; ++j) { int idx = base + j; v[j] = (idx < M) ? cnt[idx] : 0; }
  }
  int ts = 0;
#pragma unroll
  for (int j = 0; j < 8; ++j) ts += v[j];
  int incl = ts;
#pragma unroll
  for (int d = 1; d < 64; d <<= 1) { int u = __shfl_up(incl, d, 64); if (lane >= d) incl += u; }
  if (lane == 63) wsh[wid] = incl;
  __syncthreads();
  int woff = 0;
  for (int w = 0; w < wid; ++w) woff += wsh[w];
  int run = part[blockIdx.x] + woff + incl - ts;
#pragma unroll
  for (int j = 0; j < 8; ++j) {
    int idx = base + j;
    if (idx < M) rp[idx] = run;
    run += v[j];
  }
}

// ---------------- scatter edges into bucket-grouped buffer (LDS cursors) ----------------
__global__ __launch_bounds__(256) void k_scatter(const int* __restrict__ s1, const int* __restrict__ d1, int E1,
                                                 const int* __restrict__ s2, const int* __restrict__ d2, int E2,
                                                 const int* __restrict__ s3, const int* __restrict__ d3, int E3,
                                                 const int* __restrict__ rp,
                                                 unsigned* __restrict__ ebuf, int NB, int TB) {
  __shared__ int curl[MAXTB];
  int t = threadIdx.x, b = blockIdx.x;
  for (int k = t; k < TB; k += 256) curl[k] = rp[(size_t)k * NBLK + b];
  __syncthreads();
  int ET = E1 + E2 + E3;
  int CH = (ET + NBLK - 1) / NBLK;
  int lo = b * CH, hi = min(lo + CH, ET);
  for (int i = lo + t; i < hi; i += 256) {
    const int* sp; const int* dp; int j, r;
    if (i < E1) { r = 0; j = i; sp = s1; dp = d1; }
    else if (i < E1 + E2) { r = 1; j = i - E1; sp = s2; dp = d2; }
    else { r = 2; j = i - E1 - E2; sp = s3; dp = d3; }
    int dst = dp[j];
    int kb = r * NB + (dst >> 6);
    int pos = atomicAdd(&curl[kb], 1);
    ebuf[pos] = ((unsigned)(dst & 63) << 16) | (unsigned)sp[j];
  }
}

// ---------------- second level: sort each bucket by dst, emit per-dst CSR ----------------
__global__ __launch_bounds__(256) void k_bsort(const unsigned* __restrict__ ebuf,
                                               const int* __restrict__ rp,
                                               unsigned short* __restrict__ ebuf2,
                                               int* __restrict__ rp2, int* __restrict__ deg,
                                               int NB, int NM) {
  __shared__ int hist[64];
  __shared__ int cursor[64];
  int t = threadIdx.x;
  int k = blockIdx.x;
  if (t < 64) hist[t] = 0;
  __syncthreads();
  int start = rp[(size_t)k * NBLK];
  int end = rp[(size_t)(k + 1) * NBLK];
  for (int e = start + t; e < end; e += 256)
    atomicAdd(&hist[ebuf[e] >> 16], 1);
  __syncthreads();
  if (t < 64) {
    int v = hist[t];
    int incl = v;
#pragma unroll
    for (int d = 1; d < 64; d <<= 1) { int u = __shfl_up(incl, d, 64); if (t >= d) incl += u; }
    int excl = incl - v;
    cursor[t] = start + excl;
    int r = k / NB, bb = k - r * NB;
    int ld = bb * 64 + t;
    if (ld < NM) {
      rp2[r * NM + ld] = start + excl;
      deg[r * NM + ld] = v;
    }
  }
  __syncthreads();
  for (int e = start + t; e < end; e += 256) {
    unsigned p = ebuf[e];
    int pos = atomicAdd(&cursor[p >> 16], 1);
    ebuf2[pos] = (unsigned short)(p & 0xFFFF);
  }
}

// ---------------- pull aggregation (2 rows per wave, bf16 uint2 gathers, 2-edge unroll) ----------------
__global__ __launch_bounds__(256) void k_pull2(const uint2* __restrict__ mv,
                                               const int* __restrict__ rp2,
                                               const int* __restrict__ deg,
                                               const unsigned short* __restrict__ ebuf2,
                                               float* __restrict__ z, int N) {
  int lane = threadIdx.x & 63, wid = threadIdx.x >> 6;
  int half = lane >> 5, hl = lane & 31;
  int gw = blockIdx.x * 4 + wid, nw = gridDim.x * 4;
  for (int n0 = gw * 2; n0 < N; n0 += nw * 2) {
    int n = n0 + half;
    bool valid = n < N;
    int b = 0, d = 0;
    if (valid) { b = rp2[n]; d = deg[n]; }
    float ax = 0.f, ay = 0.f, az = 0.f, aw = 0.f;
    int i = 0;
    for (; i + 2 <= d; i += 2) {
      int s0 = ebuf2[b + i];
      int s1 = ebuf2[b + i + 1];
      uint2 v0 = mv[(size_t)s0 * 32 + hl];
      uint2 v1 = mv[(size_t)s1 * 32 + hl];
      ax += __uint_as_float(v0.x << 16); ay += __uint_as_float(v0.x & 0xFFFF0000u);
      az += __uint_as_float(v0.y << 16); aw += __uint_as_float(v0.y & 0xFFFF0000u);
      ax += __uint_as_float(v1.x << 16); ay += __uint_as_float(v1.x & 0xFFFF0000u);
      az += __uint_as_float(v1.y << 16); aw += __uint_as_float(v1.y & 0xFFFF0000u);
    }
    if (i < d) {
      int s0 = ebuf2[b + i];
      uint2 v0 = mv[(size_t)s0 * 32 + hl];
      ax += __uint_as_float(v0.x << 16); ay += __uint_as_float(v0.x & 0xFFFF0000u);
      az += __uint_as_float(v0.y << 16); aw += __uint_as_float(v0.y & 0xFFFF0000u);
    }
    if (valid) {
      float sc = rsqrtf(fmaxf((float)d, 1.0f));
      float4 o; o.x = ax * sc; o.y = ay * sc; o.z = az * sc; o.w = aw * sc;
      *(float4*)(z + (size_t)n * DIM + hl * 4) = o;
    }
  }
}

// ---------------- m = (h * rsqrt(deg)) @ W, bf16 output (wave handles 4 nodes per Wl pass) ----------------
__global__ __launch_bounds__(512) void k_gemm(const float* __restrict__ h,
                                              const float* __restrict__ W,
                                              const int* __restrict__ degout,
                                              unsigned* __restrict__ m16, int N) {
  __shared__ float Wl[DIM * DIM];
  for (int i = threadIdx.x; i < DIM * DIM; i += 512) Wl[i] = W[i];
  __syncthreads();
  int lane = threadIdx.x & 63, wid = threadIdx.x >> 6;
  int gw = blockIdx.x * 8 + wid, nw = gridDim.x * 8;
  for (int n0 = gw * 4; n0 < N; n0 += nw * 4) {
    int nc1 = min(n0 + 1, N - 1), nc2 = min(n0 + 2, N - 1), nc3 = min(n0 + 3, N - 1);
    const float4* h0 = (const float4*)(h + (size_t)n0 * DIM);
    const float4* h1 = (const float4*)(h + (size_t)nc1 * DIM);
    const float4* h2 = (const float4*)(h + (size_t)nc2 * DIM);
    const float4* h3 = (const float4*)(h + (size_t)nc3 * DIM);
    float ax0 = 0, ay0 = 0, ax1 = 0, ay1 = 0, ax2 = 0, ay2 = 0, ax3 = 0, ay3 = 0;
#pragma unroll 2
    for (int k4 = 0; k4 < 32; ++k4) {
      float4 u0 = h0[k4], u1 = h1[k4], u2 = h2[k4], u3 = h3[k4];
      int k = k4 * 4;
      float2 w0 = *(const float2*)&Wl[(k + 0) * DIM + 2 * lane];
      float2 w1 = *(const float2*)&Wl[(k + 1) * DIM + 2 * lane];
      float2 w2 = *(const float2*)&Wl[(k + 2) * DIM + 2 * lane];
      float2 w3 = *(const float2*)&Wl[(k + 3) * DIM + 2 * lane];
      ax0 = fmaf(u0.x, w0.x, ax0); ay0 = fmaf(u0.x, w0.y, ay0);
      ax1 = fmaf(u1.x, w0.x, ax1); ay1 = fmaf(u1.x, w0.y, ay1);
      ax2 = fmaf(u2.x, w0.x, ax2); ay2 = fmaf(u2.x, w0.y, ay2);
      ax3 = fmaf(u3.x, w0.x, ax3); ay3 = fmaf(u3.x, w0.y, ay3);
      ax0 = fmaf(u0.y, w1.x, ax0); ay0 = fmaf(u0.y, w1.y, ay0);
      ax1 = fmaf(u1.y, w1.x, ax1); ay1 = fmaf(u1.y, w1.y, ay1);
      ax2 = fmaf(u2.y, w1.x, ax2); ay2 = fmaf(u2.y, w1.y, ay2);
      ax3 = fmaf(u3.y, w1.x, ax3); ay3 = fmaf(u3.y, w1.y, ay3);
      ax0 = fmaf(u0.z, w2.x, ax0); ay0 = fmaf(u0.z, w2.y, ay0);
      ax1 = fmaf(u1.z, w2.x, ax1); ay1 = fmaf(u1.z, w2.y, ay1);
      ax2 = fmaf(u2.z, w2.x, ax2); ay2 = fmaf(u2.z, w2.y, ay2);
      ax3 = fmaf(u3.z, w2.x, ax3); ay3 = fmaf(u3.z, w2.y, ay3);
      ax0 = fmaf(u0.w, w3.x, ax0); ay0 = fmaf(u0.w, w3.y, ay0);
      ax1 = fmaf(u1.w, w3.x, ax1); ay1 = fmaf(u1.w, w3.y, ay1);
      ax2 = fmaf(u2.w, w3.x, ax2); ay2 = fmaf(u2.w, w3.y, ay2);
      ax3 = fmaf(u3.w, w3.x, ax3); ay3 = fmaf(u3.w, w3.y, ay3);
    }
    float s0 = rsqrtf(fmaxf((float)degout[n0], 1.0f));
    m16[(size_t)n0 * 64 + lane] = pack2_bf16(s0 * ax0, s0 * ay0);
    if (n0 + 1 < N) {
      float s = rsqrtf(fmaxf((float)degout[n0 + 1], 1.0f));
      m16[(size_t)(n0 + 1) * 64 + lane] = pack2_bf16(s * ax1, s * ay1);
    }
    if (n0 + 2 < N) {
      float s = rsqrtf(fmaxf((float)degout[n0 + 2], 1.0f));
      m16[(size_t)(n0 + 2) * 64 + lane] = pack2_bf16(s * ax2, s * ay2);
    }
    if (n0 + 3 < N) {
      float s = rsqrtf(fmaxf((float)degout[n0 + 3], 1.0f));
      m16[(size_t)(n0 + 3) * 64 + lane] = pack2_bf16(s * ax3, s * ay3);
    }
  }
}

// ---------------- attention scores (512 thr, 1 row/wave — round-9 form, measured best) ----------------
__global__ __launch_bounds__(512) void k_att(const float* __restrict__ z1,
                                             const float* __restrict__ z2,
                                             const float* __restrict__ attW,
                                             const float* __restrict__ attb,
                                             const float* __restrict__ attq,
                                             float* __restrict__ wsum, int N) {
  __shared__ float Wl[DIM * DIM];
  for (int i = threadIdx.x; i < DIM * DIM; i += 512) Wl[i] = attW[i];
  int lane = threadIdx.x & 63, wid = threadIdx.x >> 6;
  float b0 = attb[2 * lane], b1 = attb[2 * lane + 1];
  float q0 = attq[2 * lane], q1 = attq[2 * lane + 1];
  __syncthreads();
  int gw = blockIdx.x * 8 + wid, nw = gridDim.x * 8;
  float a1 = 0.f, a2 = 0.f;
  for (int n = gw; n < N; n += nw) {
    const float4* p1 = (const float4*)(z1 + (size_t)n * DIM);
    const float4* p2 = (const float4*)(z2 + (size_t)n * DIM);
    float c1x = 0, c1y = 0, c2x = 0, c2y = 0;
#pragma unroll 4
    for (int k4 = 0; k4 < 32; ++k4) {
      float4 u = p1[k4];
      float4 v = p2[k4];
      int k = k4 * 4;
      float2 w0 = *(const float2*)&Wl[(k + 0) * DIM + 2 * lane];
      float2 w1 = *(const float2*)&Wl[(k + 1) * DIM + 2 * lane];
      float2 w2 = *(const float2*)&Wl[(k + 2) * DIM + 2 * lane];
      float2 w3 = *(const float2*)&Wl[(k + 3) * DIM + 2 * lane];
      c1x = fmaf(u.x, w0.x, c1x); c1y = fmaf(u.x, w0.y, c1y);
      c2x = fmaf(v.x, w0.x, c2x); c2y = fmaf(v.x, w0.y, c2y);
      c1x = fmaf(u.y, w1.x, c1x); c1y = fmaf(u.y, w1.y, c1y);
      c2x = fmaf(v.y, w1.x, c2x); c2y = fmaf(v.y, w1.y, c2y);
      c1x = fmaf(u.z, w2.x, c1x); c1y = fmaf(u.z, w2.y, c1y);
      c2x = fmaf(v.z, w2.x, c2x); c2y = fmaf(v.z, w2.y, c2y);
      c1x = fmaf(u.w, w3.x, c1x); c1y = fmaf(u.w, w3.y, c1y);
      c2x = fmaf(v.w, w3.x, c2x); c2y = fmaf(v.w, w3.y, c2y);
    }
    a1 += tanhf(c1x + b0) * q0 + tanhf(c1y + b1) * q1;
    a2 += tanhf(c2x + b0) * q0 + tanhf(c2y + b1) * q1;
  }
#pragma unroll
  for (int off = 32; off; off >>= 1) {
    a1 += __shfl_down(a1, off, 64);
    a2 += __shfl_down(a2, off, 64);
  }
  __syncthreads();  // done reading Wl; reuse as scratch
  if (lane == 0) { Wl[wid] = a1; Wl[8 + wid] = a2; }
  __syncthreads();
  if (threadIdx.x == 0) {
    float s1 = 0, s2 = 0;
    for (int w = 0; w < 8; ++w) { s1 += Wl[w]; s2 += Wl[8 + w]; }
    atomicAdd(&wsum[0], s1);
    atomicAdd(&wsum[1], s2);
  }
}

// ---------------- fused: x = b1*z1 + b2*z2 (in place) + column stats for xp AND xa ----------------
// st layout: [0:128)=sum_p [128:256)=sq_p [256:384)=sum_a [384:512)=sq_a
__global__ __launch_bounds__(256) void k_comb_stats(float* __restrict__ xp,
                                                    const float* __restrict__ z2,
                                                    const float* __restrict__ xa,
                                                    const float* __restrict__ wsum,
                                                    float invNP, int np4, int na4,
                                                    float* __restrict__ st) {
  float w1 = wsum[0] * invNP, w2 = wsum[1] * invNP;
  float mx = fmaxf(w1, w2);
  float e1 = expf(w1 - mx), e2 = expf(w2 - mx);
  float inv = 1.f / (e1 + e2);
  float b1 = e1 * inv, b2 = e2 * inv;
  int t = threadIdx.x;
  int i0 = blockIdx.x * 256 + t;
  int stride = gridDim.x * 256;       // multiple of 32 -> thread's column group fixed
  float4* x4 = (float4*)xp;
  const float4* z4 = (const float4*)z2;
  const float4* a4 = (const float4*)xa;
  float s0 = 0, s1 = 0, s2 = 0, s3 = 0, q0 = 0, q1 = 0, q2 = 0, q3 = 0;
  for (int i = i0; i < np4; i += stride) {
    float4 a = x4[i], b = z4[i];
    a.x = b1 * a.x + b2 * b.x;
    a.y = b1 * a.y + b2 * b.y;
    a.z = b1 * a.z + b2 * b.z;
    a.w = b1 * a.w + b2 * b.w;
    x4[i] = a;
    s0 += a.x; s1 += a.y; s2 += a.z; s3 += a.w;
    q0 += a.x * a.x; q1 += a.y * a.y; q2 += a.z * a.z; q3 += a.w * a.w;
  }
  __shared__ float red[256 * 4];
  int c = t & 31;                      // float4-column group 0..31
  // reduce sums
  red[t * 4 + 0] = s0; red[t * 4 + 1] = s1; red[t * 4 + 2] = s2; red[t * 4 + 3] = s3;
  __syncthreads();
  if (t < 32) {
    float r0 = 0, r1 = 0, r2 = 0, r3 = 0;
    for (int j = 0; j < 8; ++j) {
      int tt = t + 32 * j;
      r0 += red[tt * 4 + 0]; r1 += red[tt * 4 + 1]; r2 += red[tt * 4 + 2]; r3 += red[tt * 4 + 3];
    }
    atomicAdd(&st[4 * t + 0], r0); atomicAdd(&st[4 * t + 1], r1);
    atomicAdd(&st[4 * t + 2], r2); atomicAdd(&st[4 * t + 3], r3);
  }
  __syncthreads();
  // reduce squares
  red[t * 4 + 0] = q0; red[t * 4 + 1] = q1; red[t * 4 + 2] = q2; red[t * 4 + 3] = q3;
  __syncthreads();
  if (t < 32) {
    float r0 = 0, r1 = 0, r2 = 0, r3 = 0;
    for (int j = 0; j < 8; ++j) {
      int tt = t + 32 * j;
      r0 += red[tt * 4 + 0]; r1 += red[tt * 4 + 1]; r2 += red[tt * 4 + 2]; r3 += red[tt * 4 + 3];
    }
    atomicAdd(&st[DIM + 4 * t + 0], r0); atomicAdd(&st[DIM + 4 * t + 1], r1);
    atomicAdd(&st[DIM + 4 * t + 2], r2); atomicAdd(&st[DIM + 4 * t + 3], r3);
  }
  __syncthreads();
  // phase 2: xa stats (read-only)
  s0 = s1 = s2 = s3 = q0 = q1 = q2 = q3 = 0;
  for (int i = i0; i < na4; i += stride) {
    float4 a = a4[i];
    s0 += a.x; s1 += a.y; s2 += a.z; s3 += a.w;
    q0 += a.x * a.x; q1 += a.y * a.y; q2 += a.z * a.z; q3 += a.w * a.w;
  }
  red[t * 4 + 0] = s0; red[t * 4 + 1] = s1; red[t * 4 + 2] = s2; red[t * 4 + 3] = s3;
  __syncthreads();
  if (t < 32) {
    float r0 = 0, r1 = 0, r2 = 0, r3 = 0;
    for (int j = 0; j < 8; ++j) {
      int tt = t + 32 * j;
      r0 += red[tt * 4 + 0]; r1 += red[tt * 4 + 1]; r2 += red[tt * 4 + 2]; r3 += red[tt * 4 + 3];
    }
    atomicAdd(&st[2 * DIM + 4 * t + 0], r0); atomicAdd(&st[2 * DIM + 4 * t + 1], r1);
    atomicAdd(&st[2 * DIM + 4 * t + 2], r2); atomicAdd(&st[2 * DIM + 4 * t + 3], r3);
  }
  __syncthreads();
  red[t * 4 + 0] = q0; red[t * 4 + 1] = q1; red[t * 4 + 2] = q2; red[t * 4 + 3] = q3;
  __syncthreads();
  if (t < 32) {
    float r0 = 0, r1 = 0, r2 = 0, r3 = 0;
    for (int j = 0; j < 8; ++j) {
      int tt = t + 32 * j;
      r0 += red[tt * 4 + 0]; r1 += red[tt * 4 + 1]; r2 += red[tt * 4 + 2]; r3 += red[tt * 4 + 3];
    }
    atomicAdd(&st[3 * DIM + 4 * t + 0], r0); atomicAdd(&st[3 * DIM + 4 * t + 1], r1);
    atomicAdd(&st[3 * DIM + 4 * t + 2], r2); atomicAdd(&st[3 * DIM + 4 * t + 3], r3);
  }
}

// ---------------- BatchNorm + row L2 normalize, wave per row, both outputs ----------------
__global__ __launch_bounds__(256) void k_post2(float* __restrict__ xp, float* __restrict__ xa,
                                               const float* __restrict__ st,
                                               const float* __restrict__ gamma,
                                               const float* __restrict__ beta,
                                               int NP, int NA) {
  int lane = threadIdx.x & 63;
  int wv = blockIdx.x * 4 + (threadIdx.x >> 6), nw = gridDim.x * 4;
  int d0 = 2 * lane, d1 = d0 + 1;
  {
    float invN = 1.f / (float)NP;
    float mu0 = st[d0] * invN, mu1 = st[d1] * invN;
    float g0 = gamma[d0] * rsqrtf(st[DIM + d0] * invN - mu0 * mu0 + 1e-5f);
    float g1 = gamma[d1] * rsqrtf(st[DIM + d1] * invN - mu1 * mu1 + 1e-5f);
    float b0 = beta[d0], b1 = beta[d1];
    for (int n = wv; n < NP; n += nw) {
      float2 v = *(float2*)(xp + (size_t)n * DIM + d0);
      float y0 = fmaf(v.x - mu0, g0, b0);
      float y1 = fmaf(v.y - mu1, g1, b1);
      float p = y0 * y0 + y1 * y1;
#pragma unroll
      for (int off = 32; off; off >>= 1) p += __shfl_xor(p, off, 64);
      float r = rsqrtf(p + 1e-12f);
      float2 o; o.x = y0 * r; o.y = y1 * r;
      *(float2*)(xp + (size_t)n * DIM + d0) = o;
    }
  }
  {
    float invN = 1.f / (float)NA;
    float mu0 = st[2 * DIM + d0] * invN, mu1 = st[2 * DIM + d1] * invN;
    float g0 = gamma[d0] * rsqrtf(st[3 * DIM + d0] * invN - mu0 * mu0 + 1e-5f);
    float g1 = gamma[d1] * rsqrtf(st[3 * DIM + d1] * invN - mu1 * mu1 + 1e-5f);
    float b0 = beta[d0], b1 = beta[d1];
    for (int n = wv; n < NA; n += nw) {
      float2 v = *(float2*)(xa + (size_t)n * DIM + d0);
      float y0 = fmaf(v.x - mu0, g0, b0);
      float y1 = fmaf(v.y - mu1, g1, b1);
      float p = y0 * y0 + y1 * y1;
#pragma unroll
      for (int off = 32; off; off >>= 1) p += __shfl_xor(p, off, 64);
      float r = rsqrtf(p + 1e-12f);
      float2 o; o.x = y0 * r; o.y = y1 * r;
      *(float2*)(xa + (size_t)n * DIM + d0) = o;
    }
  }
}

extern "C" void kernel_launch(void* const* d_in, const int* in_sizes, int n_in,
                              void* d_out, int out_size, void* d_ws, size_t ws_size,
                              hipStream_t stream) {
  const float* h_paper  = (const float*)d_in[0];
  const float* h_author = (const float*)d_in[1];
  const float* W_r1 = (const float*)d_in[2];
  const float* W_r2 = (const float*)d_in[3];
  const float* W_r3 = (const float*)d_in[4];
  const float* att_W = (const float*)d_in[5];
  const float* att_b = (const float*)d_in[6];
  const float* att_q = (const float*)d_in[7];
  const float* bn_g = (const float*)d_in[8];
  const float* bn_b = (const float*)d_in[9];
  const int* src_r1 = (const int*)d_in[10];
  const int* dst_r1 = (const int*)d_in[11];
  const int* src_r2 = (const int*)d_in[12];
  const int* dst_r2 = (const int*)d_in[13];
  const int* src_r3 = (const int*)d_in[14];
  const int* dst_r3 = (const int*)d_in[15];

  int NP = in_sizes[0] / DIM;
  int NA = in_sizes[1] / DIM;
  int E1 = in_sizes[10], E2 = in_sizes[12], E3 = in_sizes[14];
  int ET = E1 + E2 + E3;
  int NM = NP > NA ? NP : NA;
  int NB = (NM + 63) >> 6;              // buckets per relation (dst/64)
  int TB = 3 * NB;                      // total buckets
  int M = TB * NBLK;                    // offset-matrix length
  int B = (M + 2047) / 2048;            // scan partial blocks (<=256)

  char* ws = (char*)d_ws;
  size_t off = 0;
  unsigned* m16 = (unsigned*)(ws + off); off += align256((size_t)NM * 64 * 4);   // bf16-packed m
  float* z2    = (float*)(ws + off);    off += align256((size_t)NP * DIM * 4);
  unsigned* ebuf = (unsigned*)(ws + off); off += align256((size_t)ET * 4);
  unsigned short* ebuf2 = (unsigned short*)(ws + off); off += align256((size_t)ET * 2);
  int* Hmat    = (int*)(ws + off);      off += align256((size_t)M * 4);
  int* rp      = (int*)(ws + off);      off += align256(((size_t)M + 1) * 4);
  int* rp2     = (int*)(ws + off);      off += align256((size_t)3 * NM * 4);
  int* deg     = (int*)(ws + off);      off += align256((size_t)3 * NM * 4);
  int* part    = (int*)(ws + off);      off += align256(256 * 4);
  size_t zoff = off;  // zero-initialized region
  int* dout    = (int*)(ws + off);      off += (size_t)3 * NM * 4;
  float* wsum  = (float*)(ws + off);    off += 2 * 4;
  float* stats = (float*)(ws + off);    off += 4 * DIM * 4;
  size_t zbytes = off - zoff;

  float* xp = (float*)d_out;                       // papers (z_p1 staging)
  float* xa = (float*)d_out + (size_t)NP * DIM;    // authors (z_a1 staging)

  hipMemsetAsync(ws + zoff, 0, zbytes, stream);

  // out-degrees for GEMM pre-scale
  k_dout<<<2048, 256, 0, stream>>>(src_r1, E1, src_r2, E2, src_r3, E3, dout, NM);

  // bucket partition: histogram -> scan -> scatter -> per-bucket dst sort
  k_hist<<<NBLK, 256, 0, stream>>>(dst_r1, E1, dst_r2, E2, dst_r3, E3, Hmat, NB, TB);
  k_scan1<<<B, 256, 0, stream>>>(Hmat, part, M);
  k_scan2<<<1, 256, 0, stream>>>(part, B, rp, M);
  k_scan3<<<B, 256, 0, stream>>>(Hmat, part, rp, M);
  k_scatter<<<NBLK, 256, 0, stream>>>(src_r1, dst_r1, E1, src_r2, dst_r2, E2,
                                      src_r3, dst_r3, E3, rp, ebuf, NB, TB);
  k_bsort<<<TB, 256, 0, stream>>>(ebuf, rp, ebuf2, rp2, deg, NB, NM);

  const uint2* mv = (const uint2*)m16;
  // r1: author -> paper (z_p1 -> xp)
  k_gemm<<<512, 512, 0, stream>>>(h_author, W_r1, dout, m16, NA);
  k_pull2<<<2048, 256, 0, stream>>>(mv, rp2, deg, ebuf2, xp, NP);
  // r2: paper -> paper (z_p2 -> ws)
  k_gemm<<<512, 512, 0, stream>>>(h_paper, W_r2, dout + NM, m16, NP);
  k_pull2<<<2048, 256, 0, stream>>>(mv, rp2 + NM, deg + NM, ebuf2, z2, NP);
  // r3: author -> author (z_a1 -> xa; softmax over 1 relation == identity)
  k_gemm<<<512, 512, 0, stream>>>(h_author, W_r3, dout + 2 * NM, m16, NA);
  k_pull2<<<2048, 256, 0, stream>>>(mv, rp2 + 2 * NM, deg + 2 * NM, ebuf2, xa, NA);

  // semantic attention (papers)
  k_att<<<512, 512, 0, stream>>>(xp, z2, att_W, att_b, att_q, wsum, NP);
  // fused combine + BN stats (both outputs)
  k_comb_stats<<<512, 256, 0, stream>>>(xp, z2, xa, wsum, 1.0f / (float)NP,
                                        NP * DIM / 4, NA * DIM / 4, stats);

  // BN apply + row L2 for both outputs
  k_post2<<<2048, 256, 0, stream>>>(xp, xa, stats, bn_g, bn_b, NP, NA);
}